// Round 1
// baseline (2996.418 us; speedup 1.0000x reference)
//
#include <hip/hip_runtime.h>
#include <math.h>

#define EPS_LN 1e-5f

// Problem dims (fixed by harness)
#define B_  2
#define ST_ 2048
#define SI_ 1024
#define K_  64
#define D_  768
#define E_  256

// ---------------------------------------------------------------------------
// LN xhat: one block per row, writes (x-mu)*rsqrt(var+eps)
// ---------------------------------------------------------------------------
__global__ __launch_bounds__(256) void ln_xhat_kernel(const float* __restrict__ x,
                                                      float* __restrict__ xhat) {
    int row = blockIdx.x;
    const float* xr = x + (size_t)row * D_;
    float* xo = xhat + (size_t)row * D_;
    int tid = threadIdx.x;
    __shared__ float red[256];
    float s = 0.f;
    for (int d = tid; d < D_; d += 256) s += xr[d];
    red[tid] = s; __syncthreads();
    for (int off = 128; off > 0; off >>= 1) { if (tid < off) red[tid] += red[tid + off]; __syncthreads(); }
    float mu = red[0] / (float)D_;
    __syncthreads();
    float v = 0.f;
    for (int d = tid; d < D_; d += 256) { float t = xr[d] - mu; v += t * t; }
    red[tid] = v; __syncthreads();
    for (int off = 128; off > 0; off >>= 1) { if (tid < off) red[tid] += red[tid + off]; __syncthreads(); }
    float rstd = rsqrtf(red[0] / (float)D_ + EPS_LN);
    for (int d = tid; d < D_; d += 256) xo[d] = (xr[d] - mu) * rstd;
}

// ---------------------------------------------------------------------------
// Weight folding: Wf[d,e] = g[d]*W[d,e]
// ---------------------------------------------------------------------------
__global__ void fold_w_kernel(const float* __restrict__ g, const float* __restrict__ W,
                              float* __restrict__ Wf, int D, int E) {
    int i = blockIdx.x * 256 + threadIdx.x;
    if (i < D * E) Wf[i] = g[i / E] * W[i];
}

// bias folding: bf[e] = sum_d bln[d]*W[d,e] + (wb ? wb[e] : 0)
__global__ void fold_b_kernel(const float* __restrict__ bln, const float* __restrict__ W,
                              const float* __restrict__ wb, float* __restrict__ bf, int D, int E) {
    int e = blockIdx.x * 256 + threadIdx.x;
    if (e < E) {
        float s = wb ? wb[e] : 0.f;
        for (int d = 0; d < D; ++d) s += bln[d] * W[(size_t)d * E + e];
        bf[e] = s;
    }
}

// ---------------------------------------------------------------------------
// Generic tiled SGEMM: C[M,N] = A[M,K]@B[K,N] (+bias[N]) (+= if accumulate)
// M%64==0, N%64==0, K%16==0. grid (N/64, M/64), block (16,16)
// ---------------------------------------------------------------------------
__global__ __launch_bounds__(256) void sgemm_kernel(const float* __restrict__ A,
                                                    const float* __restrict__ Bm,
                                                    const float* __restrict__ bias,
                                                    float* __restrict__ C,
                                                    int M, int N, int Kd, int accumulate) {
    __shared__ float As[16][65];
    __shared__ float Bs[16][64];
    int tx = threadIdx.x, ty = threadIdx.y;
    int tid = ty * 16 + tx;
    int row0 = blockIdx.y * 64;
    int col0 = blockIdx.x * 64;
    float acc[4][4] = {};
    for (int k0 = 0; k0 < Kd; k0 += 16) {
        {
            int e = tid * 4;
            int r = e >> 4, kk = e & 15;
            float4 av = *(const float4*)(A + (size_t)(row0 + r) * Kd + k0 + kk);
            As[kk + 0][r] = av.x; As[kk + 1][r] = av.y; As[kk + 2][r] = av.z; As[kk + 3][r] = av.w;
        }
        {
            int e = tid * 4;
            int kk = e >> 6, c = e & 63;
            *(float4*)&Bs[kk][c] = *(const float4*)(Bm + (size_t)(k0 + kk) * N + col0 + c);
        }
        __syncthreads();
        #pragma unroll
        for (int kk = 0; kk < 16; ++kk) {
            float a[4], b[4];
            #pragma unroll
            for (int i = 0; i < 4; ++i) a[i] = As[kk][ty + 16 * i];
            #pragma unroll
            for (int j = 0; j < 4; ++j) b[j] = Bs[kk][tx + 16 * j];
            #pragma unroll
            for (int i = 0; i < 4; ++i)
                #pragma unroll
                for (int j = 0; j < 4; ++j)
                    acc[i][j] += a[i] * b[j];
        }
        __syncthreads();
    }
    #pragma unroll
    for (int i = 0; i < 4; ++i) {
        int r = row0 + ty + 16 * i;
        #pragma unroll
        for (int j = 0; j < 4; ++j) {
            int c = col0 + tx + 16 * j;
            float v = acc[i][j];
            if (bias) v += bias[c];
            if (accumulate) C[(size_t)r * N + c] += v;
            else C[(size_t)r * N + c] = v;
        }
    }
}

// ---------------------------------------------------------------------------
// Cross + edge kernel (dominant): per (b,k,s-tile of 64):
//   z[s,j] = sum_e (s[s,e]*t[k,e])*W3[e,j] + a1[s,j] + c2[k,j]
//   e[s]   = softsign(sum_j gelu(z)*m2w[j] + m2b) * mask[s]
// grid (S/64, K, B), block (32,8)
// ---------------------------------------------------------------------------
__global__ __launch_bounds__(256) void cross_edge_kernel(
    const float* __restrict__ sP,   // [B][S][E]
    const float* __restrict__ a1P,  // [B][S][E]
    const float* __restrict__ tP,   // [B][K][E]
    const float* __restrict__ c2P,  // [B][K][E]
    const float* __restrict__ W3,   // [E][E]
    const float* __restrict__ m2w,  // [E]
    const float* __restrict__ m2b,  // [1]
    const float* __restrict__ mask, // [B][S]
    float* __restrict__ outE,       // [B][S][K]
    int S)
{
    __shared__ float As[16][65];
    __shared__ float Bs[16][256];
    __shared__ float tv[256], c2v[256], m2s[256];
    int tx = threadIdx.x;  // 0..31
    int ty = threadIdx.y;  // 0..7
    int tid = ty * 32 + tx;
    int s0 = blockIdx.x * 64;
    int k  = blockIdx.y;
    int b  = blockIdx.z;

    tv[tid]  = tP [((size_t)b * K_ + k) * E_ + tid];
    c2v[tid] = c2P[((size_t)b * K_ + k) * E_ + tid];
    m2s[tid] = m2w[tid];
    __syncthreads();

    float acc[8][8] = {};
    const float* sBase = sP + ((size_t)b * S + s0) * E_;
    for (int e0 = 0; e0 < E_; e0 += 16) {
        {
            int e = tid * 4;
            int r = e >> 4, ee = e & 15;
            float4 av = *(const float4*)(sBase + (size_t)r * E_ + e0 + ee);
            As[ee + 0][r] = av.x * tv[e0 + ee + 0];
            As[ee + 1][r] = av.y * tv[e0 + ee + 1];
            As[ee + 2][r] = av.z * tv[e0 + ee + 2];
            As[ee + 3][r] = av.w * tv[e0 + ee + 3];
        }
        #pragma unroll
        for (int q = 0; q < 4; ++q) {
            int e = tid * 4 + q * 1024;
            int ee = e >> 8, c = e & 255;
            *(float4*)&Bs[ee][c] = *(const float4*)(W3 + (size_t)(e0 + ee) * E_ + c);
        }
        __syncthreads();
        #pragma unroll
        for (int kk = 0; kk < 16; ++kk) {
            float a[8], bb[8];
            #pragma unroll
            for (int i = 0; i < 8; ++i) a[i] = As[kk][ty + 8 * i];
            #pragma unroll
            for (int j = 0; j < 8; ++j) bb[j] = Bs[kk][tx + 32 * j];
            #pragma unroll
            for (int i = 0; i < 8; ++i)
                #pragma unroll
                for (int j = 0; j < 8; ++j)
                    acc[i][j] += a[i] * bb[j];
        }
        __syncthreads();
    }
    // epilogue: +a1 +c2, exact gelu, dot with m2w, reduce over tx
    const float* a1Base = a1P + ((size_t)b * S + s0) * E_;
    float m2bv = m2b[0];
    float p[8];
    #pragma unroll
    for (int i = 0; i < 8; ++i) {
        int r = ty + 8 * i;
        float pi = 0.f;
        #pragma unroll
        for (int j = 0; j < 8; ++j) {
            int c = tx + 32 * j;
            float z = acc[i][j] + a1Base[(size_t)r * E_ + c] + c2v[c];
            float h = 0.5f * z * (1.0f + erff(z * 0.70710678118654752f));
            pi += h * m2s[c];
        }
        p[i] = pi;
    }
    #pragma unroll
    for (int i = 0; i < 8; ++i) {
        float v = p[i];
        for (int off = 16; off > 0; off >>= 1) v += __shfl_xor(v, off, 64);
        p[i] = v;
    }
    if (tx == 0) {
        #pragma unroll
        for (int i = 0; i < 8; ++i) {
            int r = s0 + ty + 8 * i;
            float e = p[i] + m2bv;
            e = e / (1.0f + fabsf(e));
            e *= mask[(size_t)b * S + r];
            outE[((size_t)b * S + r) * K_ + k] = e;
        }
    }
}

// ---------------------------------------------------------------------------
// rowsum[b*K+k] = sum_s E[b,s,k]
// ---------------------------------------------------------------------------
__global__ __launch_bounds__(256) void rowsum_kernel(const float* __restrict__ E,
                                                     float* __restrict__ out, int S) {
    __shared__ float red[256];
    int idx = blockIdx.x; int b = idx >> 6; int k = idx & 63;
    int tid = threadIdx.x;
    float s = 0.f;
    for (int ss = tid; ss < S; ss += 256) s += E[((size_t)b * S + ss) * K_ + k];
    red[tid] = s; __syncthreads();
    for (int off = 128; off > 0; off >>= 1) { if (tid < off) red[tid] += red[tid + off]; __syncthreads(); }
    if (tid == 0) out[idx] = red[0];
}

// ---------------------------------------------------------------------------
// G[b,k,d] += sum_s E[b,s,k]*Xh[b,s,d];  R[b,k,d] += sum_s E[b,s,k]*Xr[b,s,d]
// grid (S/sPerBlock, D/64, B), block (16,16); atomic accumulate
// ---------------------------------------------------------------------------
__global__ __launch_bounds__(256) void einsum_kernel(
    const float* __restrict__ E,  const float* __restrict__ Xh,
    const float* __restrict__ Xr, float* __restrict__ G,
    float* __restrict__ R, int S, int sPerBlock)
{
    __shared__ float Es[64][68];
    __shared__ float Hs[64][68];
    __shared__ float Rs[64][68];
    int tx = threadIdx.x, ty = threadIdx.y;
    int tid = ty * 16 + tx;
    int d0 = blockIdx.y * 64;
    int b  = blockIdx.z;
    int sStart = blockIdx.x * sPerBlock;
    float accG[4][4] = {}, accR[4][4] = {};
    int ss = tid >> 2, kk0 = (tid & 3) * 16;
    for (int s1 = sStart; s1 < sStart + sPerBlock; s1 += 64) {
        #pragma unroll
        for (int q = 0; q < 4; ++q)
            *(float4*)&Es[ss][kk0 + q * 4] = *(const float4*)(E + ((size_t)b * S + s1 + ss) * K_ + kk0 + q * 4);
        #pragma unroll
        for (int q = 0; q < 4; ++q) {
            *(float4*)&Hs[ss][kk0 + q * 4] = *(const float4*)(Xh + ((size_t)b * S + s1 + ss) * D_ + d0 + kk0 + q * 4);
            *(float4*)&Rs[ss][kk0 + q * 4] = *(const float4*)(Xr + ((size_t)b * S + s1 + ss) * D_ + d0 + kk0 + q * 4);
        }
        __syncthreads();
        for (int s2 = 0; s2 < 64; ++s2) {
            float ev[4], hv[4], rv[4];
            #pragma unroll
            for (int i = 0; i < 4; ++i) ev[i] = Es[s2][ty + 16 * i];
            #pragma unroll
            for (int j = 0; j < 4; ++j) { hv[j] = Hs[s2][tx + 16 * j]; rv[j] = Rs[s2][tx + 16 * j]; }
            #pragma unroll
            for (int i = 0; i < 4; ++i)
                #pragma unroll
                for (int j = 0; j < 4; ++j) {
                    accG[i][j] += ev[i] * hv[j];
                    accR[i][j] += ev[i] * rv[j];
                }
        }
        __syncthreads();
    }
    #pragma unroll
    for (int i = 0; i < 4; ++i)
        #pragma unroll
        for (int j = 0; j < 4; ++j) {
            size_t o = ((size_t)b * K_ + ty + 16 * i) * D_ + d0 + tx + 16 * j;
            atomicAdd(&G[o], accG[i][j]);
            atomicAdd(&R[o], accR[i][j]);
        }
}

// ---------------------------------------------------------------------------
// Final LN: grid 256 blocks; idx<128 -> latent_state row, else latent_value row
// ---------------------------------------------------------------------------
__global__ __launch_bounds__(256) void final_ln_kernel(
    const float* __restrict__ stateTmp, const float* __restrict__ Racc,
    const float* __restrict__ rs_t, const float* __restrict__ rs_i,
    const float* __restrict__ b_tspf, const float* __restrict__ b_ispf,
    const float* __restrict__ state_init, const float* __restrict__ value_init,
    const float* __restrict__ stn_g, const float* __restrict__ stn_b,
    const float* __restrict__ vn_g, const float* __restrict__ vn_b,
    float* __restrict__ outState, float* __restrict__ outValue)
{
    __shared__ float pre[D_];
    __shared__ float red[256];
    int idx = blockIdx.x;
    int row = idx & 127;
    int isVal = idx >> 7;
    int tid = threadIdx.x;
    if (!isVal) {
        float rt = rs_t[row], ri = rs_i[row];
        for (int d = tid; d < D_; d += 256)
            pre[d] = stateTmp[(size_t)row * D_ + d] + rt * b_tspf[d] + ri * b_ispf[d]
                   + state_init[(size_t)row * D_ + d];
    } else {
        for (int d = tid; d < D_; d += 256)
            pre[d] = Racc[(size_t)row * D_ + d] + value_init[(size_t)row * D_ + d];
    }
    __syncthreads();
    float s = 0.f;
    for (int d = tid; d < D_; d += 256) s += pre[d];
    red[tid] = s; __syncthreads();
    for (int off = 128; off > 0; off >>= 1) { if (tid < off) red[tid] += red[tid + off]; __syncthreads(); }
    float mu = red[0] / (float)D_;
    __syncthreads();
    float v = 0.f;
    for (int d = tid; d < D_; d += 256) { float t = pre[d] - mu; v += t * t; }
    red[tid] = v; __syncthreads();
    for (int off = 128; off > 0; off >>= 1) { if (tid < off) red[tid] += red[tid + off]; __syncthreads(); }
    float rstd = rsqrtf(red[0] / (float)D_ + EPS_LN);
    const float* g  = isVal ? vn_g : stn_g;
    const float* bb = isVal ? vn_b : stn_b;
    float* o = (isVal ? outValue : outState) + (size_t)row * D_;
    for (int d = tid; d < D_; d += 256) o[d] = (pre[d] - mu) * rstd * g[d] + bb[d];
}

// ---------------------------------------------------------------------------
extern "C" void kernel_launch(void* const* d_in, const int* in_sizes, int n_in,
                              void* d_out, int out_size, void* d_ws, size_t ws_size,
                              hipStream_t stream) {
    const float* text_values  = (const float*)d_in[0];
    const float* image_values = (const float*)d_in[1];
    const float* lstate_init  = (const float*)d_in[2];
    const float* lvalue_init  = (const float*)d_in[3];
    const float* text_mask    = (const float*)d_in[4];
    const float* image_mask   = (const float*)d_in[5];
    const float* t_sn_g = (const float*)d_in[6];
    const float* t_sn_b = (const float*)d_in[7];
    const float* t_tn_g = (const float*)d_in[8];
    const float* t_tn_b = (const float*)d_in[9];
    const float* t_su_w = (const float*)d_in[10];
    const float* t_su_b = (const float*)d_in[11];
    const float* t_tp_w = (const float*)d_in[12];
    const float* t_tp_b = (const float*)d_in[13];
    const float* t_m1_w = (const float*)d_in[14];
    const float* t_m1_b = (const float*)d_in[15];
    const float* t_m2_w = (const float*)d_in[16];
    const float* t_m2_b = (const float*)d_in[17];
    const float* i_sn_g = (const float*)d_in[18];
    const float* i_sn_b = (const float*)d_in[19];
    const float* i_tn_g = (const float*)d_in[20];
    const float* i_tn_b = (const float*)d_in[21];
    const float* i_su_w = (const float*)d_in[22];
    const float* i_su_b = (const float*)d_in[23];
    const float* i_tp_w = (const float*)d_in[24];
    const float* i_tp_b = (const float*)d_in[25];
    const float* i_m1_w = (const float*)d_in[26];
    const float* i_m1_b = (const float*)d_in[27];
    const float* i_m2_w = (const float*)d_in[28];
    const float* i_m2_b = (const float*)d_in[29];
    const float* tsn_g = (const float*)d_in[30];
    const float* tsn_b = (const float*)d_in[31];
    const float* isn_g = (const float*)d_in[32];
    const float* isn_b = (const float*)d_in[33];
    const float* stn_g = (const float*)d_in[34];
    const float* stn_b = (const float*)d_in[35];
    const float* vn_g  = (const float*)d_in[36];
    const float* vn_b  = (const float*)d_in[37];
    const float* tsp_w = (const float*)d_in[38];
    const float* tsp_b = (const float*)d_in[39];
    const float* isp_w = (const float*)d_in[40];
    const float* isp_b = (const float*)d_in[41];

    float* ws = (float*)d_ws;
    size_t o = 0;
    float* xhat_text  = ws + o; o += (size_t)B_ * ST_ * D_;
    float* xhat_image = ws + o; o += (size_t)B_ * SI_ * D_;
    float* xhat_lat   = ws + o; o += (size_t)B_ * K_  * D_;
    float* W_su_t = ws + o; o += (size_t)D_ * E_;
    float* W_su_i = ws + o; o += (size_t)D_ * E_;
    float* W_tp_t = ws + o; o += (size_t)D_ * E_;
    float* W_tp_i = ws + o; o += (size_t)D_ * E_;
    float* W_tspf = ws + o; o += (size_t)D_ * D_;
    float* W_ispf = ws + o; o += (size_t)D_ * D_;
    float* b_su_t = ws + o; o += E_;
    float* b_su_i = ws + o; o += E_;
    float* b_tp_t = ws + o; o += E_;
    float* b_tp_i = ws + o; o += E_;
    float* b_tspf = ws + o; o += D_;
    float* b_ispf = ws + o; o += D_;
    float* s_text  = ws + o; o += (size_t)B_ * ST_ * E_;
    float* s_image = ws + o; o += (size_t)B_ * SI_ * E_;
    float* a1_text  = ws + o; o += (size_t)B_ * ST_ * E_;
    float* a1_image = ws + o; o += (size_t)B_ * SI_ * E_;
    float* t_t  = ws + o; o += (size_t)B_ * K_ * E_;
    float* t_i  = ws + o; o += (size_t)B_ * K_ * E_;
    float* c2_t = ws + o; o += (size_t)B_ * K_ * E_;
    float* c2_i = ws + o; o += (size_t)B_ * K_ * E_;
    // zero-initialized accumulation block (contiguous)
    float* Gt   = ws + o; o += (size_t)B_ * K_ * D_;
    float* Gi   = ws + o; o += (size_t)B_ * K_ * D_;
    float* Racc = ws + o; o += (size_t)B_ * K_ * D_;
    float* rs_t = ws + o; o += B_ * K_;
    float* rs_i = ws + o; o += B_ * K_;
    size_t zeroBytes = (3 * (size_t)B_ * K_ * D_ + 2 * B_ * K_) * sizeof(float);
    float* state_tmp = ws + o; o += (size_t)B_ * K_ * D_;

    float* outState = (float*)d_out;                       // [B,K,D]
    float* outValue = (float*)d_out + (size_t)B_ * K_ * D_;
    float* t2l = (float*)d_out + 2 * (size_t)B_ * K_ * D_;             // [B,ST,K]
    float* i2l = t2l + (size_t)B_ * ST_ * K_;                          // [B,SI,K]

    // --- fold weights/biases ---
    fold_w_kernel<<<(D_ * E_ + 255) / 256, 256, 0, stream>>>(t_sn_g, t_su_w, W_su_t, D_, E_);
    fold_w_kernel<<<(D_ * E_ + 255) / 256, 256, 0, stream>>>(i_sn_g, i_su_w, W_su_i, D_, E_);
    fold_w_kernel<<<(D_ * E_ + 255) / 256, 256, 0, stream>>>(t_tn_g, t_tp_w, W_tp_t, D_, E_);
    fold_w_kernel<<<(D_ * E_ + 255) / 256, 256, 0, stream>>>(i_tn_g, i_tp_w, W_tp_i, D_, E_);
    fold_w_kernel<<<(D_ * D_ + 255) / 256, 256, 0, stream>>>(tsn_g, tsp_w, W_tspf, D_, D_);
    fold_w_kernel<<<(D_ * D_ + 255) / 256, 256, 0, stream>>>(isn_g, isp_w, W_ispf, D_, D_);
    fold_b_kernel<<<1, 256, 0, stream>>>(t_sn_b, t_su_w, t_su_b, b_su_t, D_, E_);
    fold_b_kernel<<<1, 256, 0, stream>>>(i_sn_b, i_su_w, i_su_b, b_su_i, D_, E_);
    fold_b_kernel<<<1, 256, 0, stream>>>(t_tn_b, t_tp_w, t_tp_b, b_tp_t, D_, E_);
    fold_b_kernel<<<1, 256, 0, stream>>>(i_tn_b, i_tp_w, i_tp_b, b_tp_i, D_, E_);
    fold_b_kernel<<<3, 256, 0, stream>>>(tsn_b, tsp_w, tsp_b, b_tspf, D_, D_);
    fold_b_kernel<<<3, 256, 0, stream>>>(isn_b, isp_w, isp_b, b_ispf, D_, D_);

    // --- xhat ---
    ln_xhat_kernel<<<B_ * ST_, 256, 0, stream>>>(text_values, xhat_text);
    ln_xhat_kernel<<<B_ * SI_, 256, 0, stream>>>(image_values, xhat_image);
    ln_xhat_kernel<<<B_ * K_,  256, 0, stream>>>(lvalue_init, xhat_lat);

    dim3 blk16(16, 16);
    // s projections: [B*S,768]@[768,256]
    sgemm_kernel<<<dim3(E_ / 64, B_ * ST_ / 64), blk16, 0, stream>>>(xhat_text, W_su_t, b_su_t, s_text, B_ * ST_, E_, D_, 0);
    sgemm_kernel<<<dim3(E_ / 64, B_ * SI_ / 64), blk16, 0, stream>>>(xhat_image, W_su_i, b_su_i, s_image, B_ * SI_, E_, D_, 0);
    // t projections: [B*K,768]@[768,256]
    sgemm_kernel<<<dim3(E_ / 64, B_ * K_ / 64), blk16, 0, stream>>>(xhat_lat, W_tp_t, b_tp_t, t_t, B_ * K_, E_, D_, 0);
    sgemm_kernel<<<dim3(E_ / 64, B_ * K_ / 64), blk16, 0, stream>>>(xhat_lat, W_tp_i, b_tp_i, t_i, B_ * K_, E_, D_, 0);
    // a1 = s @ W1 (m1_w rows 0..255)
    sgemm_kernel<<<dim3(E_ / 64, B_ * ST_ / 64), blk16, 0, stream>>>(s_text, t_m1_w, nullptr, a1_text, B_ * ST_, E_, E_, 0);
    sgemm_kernel<<<dim3(E_ / 64, B_ * SI_ / 64), blk16, 0, stream>>>(s_image, i_m1_w, nullptr, a1_image, B_ * SI_, E_, E_, 0);
    // c2 = t @ W2 + m1_b (m1_w rows 256..511)
    sgemm_kernel<<<dim3(E_ / 64, B_ * K_ / 64), blk16, 0, stream>>>(t_t, t_m1_w + (size_t)E_ * E_, t_m1_b, c2_t, B_ * K_, E_, E_, 0);
    sgemm_kernel<<<dim3(E_ / 64, B_ * K_ / 64), blk16, 0, stream>>>(t_i, i_m1_w + (size_t)E_ * E_, i_m1_b, c2_i, B_ * K_, E_, E_, 0);

    // --- cross + edge (dominant) ---
    dim3 blkCross(32, 8);
    cross_edge_kernel<<<dim3(ST_ / 64, K_, B_), blkCross, 0, stream>>>(
        s_text, a1_text, t_t, c2_t, t_m1_w + 2 * (size_t)E_ * E_, t_m2_w, t_m2_b, text_mask, t2l, ST_);
    cross_edge_kernel<<<dim3(SI_ / 64, K_, B_), blkCross, 0, stream>>>(
        s_image, a1_image, t_i, c2_i, i_m1_w + 2 * (size_t)E_ * E_, i_m2_w, i_m2_b, image_mask, i2l, SI_);

    // --- aggregation ---
    hipMemsetAsync(Gt, 0, zeroBytes, stream);
    rowsum_kernel<<<B_ * K_, 256, 0, stream>>>(t2l, rs_t, ST_);
    rowsum_kernel<<<B_ * K_, 256, 0, stream>>>(i2l, rs_i, SI_);
    einsum_kernel<<<dim3(ST_ / 256, D_ / 64, B_), blk16, 0, stream>>>(t2l, xhat_text, text_values, Gt, Racc, ST_, 256);
    einsum_kernel<<<dim3(SI_ / 256, D_ / 64, B_), blk16, 0, stream>>>(i2l, xhat_image, image_values, Gi, Racc, SI_, 256);

    // state_tmp = Gt@W_tspf + Gi@W_ispf   ([128,768]@[768,768])
    sgemm_kernel<<<dim3(D_ / 64, B_ * K_ / 64), blk16, 0, stream>>>(Gt, W_tspf, nullptr, state_tmp, B_ * K_, D_, D_, 0);
    sgemm_kernel<<<dim3(D_ / 64, B_ * K_ / 64), blk16, 0, stream>>>(Gi, W_ispf, nullptr, state_tmp, B_ * K_, D_, D_, 1);

    // --- final LN ---
    final_ln_kernel<<<2 * B_ * K_, 256, 0, stream>>>(
        state_tmp, Racc, rs_t, rs_i, b_tspf, b_ispf,
        lstate_init, lvalue_init, stn_g, stn_b, vn_g, vn_b, outState, outValue);
}

// Round 2
// 1078.167 us; speedup vs baseline: 2.7792x; 2.7792x over previous
//
#include <hip/hip_runtime.h>
#include <math.h>

#define EPS_LN 1e-5f

// Problem dims (fixed by harness)
#define B_  2
#define ST_ 2048
#define SI_ 1024
#define K_  64
#define D_  768
#define E_  256

typedef __bf16 bf16x8 __attribute__((ext_vector_type(8)));
typedef float  f32x4  __attribute__((ext_vector_type(4)));

__device__ inline unsigned short f2bf(float x) {
    unsigned int u = __float_as_uint(x);
    unsigned int r = (u + 0x7FFFu + ((u >> 16) & 1u)) >> 16;
    return (unsigned short)r;
}

// ---------------------------------------------------------------------------
// LN xhat: one block per row, writes (x-mu)*rsqrt(var+eps)
// ---------------------------------------------------------------------------
__global__ __launch_bounds__(256) void ln_xhat_kernel(const float* __restrict__ x,
                                                      float* __restrict__ xhat) {
    int row = blockIdx.x;
    const float* xr = x + (size_t)row * D_;
    float* xo = xhat + (size_t)row * D_;
    int tid = threadIdx.x;
    __shared__ float red[256];
    float s = 0.f;
    for (int d = tid; d < D_; d += 256) s += xr[d];
    red[tid] = s; __syncthreads();
    for (int off = 128; off > 0; off >>= 1) { if (tid < off) red[tid] += red[tid + off]; __syncthreads(); }
    float mu = red[0] / (float)D_;
    __syncthreads();
    float v = 0.f;
    for (int d = tid; d < D_; d += 256) { float t = xr[d] - mu; v += t * t; }
    red[tid] = v; __syncthreads();
    for (int off = 128; off > 0; off >>= 1) { if (tid < off) red[tid] += red[tid + off]; __syncthreads(); }
    float rstd = rsqrtf(red[0] / (float)D_ + EPS_LN);
    for (int d = tid; d < D_; d += 256) xo[d] = (xr[d] - mu) * rstd;
}

// ---------------------------------------------------------------------------
// Weight folding: Wf[d,e] = g[d]*W[d,e]
// ---------------------------------------------------------------------------
__global__ void fold_w_kernel(const float* __restrict__ g, const float* __restrict__ W,
                              float* __restrict__ Wf, int D, int E) {
    int i = blockIdx.x * 256 + threadIdx.x;
    if (i < D * E) Wf[i] = g[i / E] * W[i];
}

// bias folding: bf[e] = sum_d bln[d]*W[d,e] + (wb ? wb[e] : 0). grid = E/64
__global__ __launch_bounds__(256) void fold_b_kernel(const float* __restrict__ bln, const float* __restrict__ W,
                              const float* __restrict__ wb, float* __restrict__ bf, int D, int E) {
    __shared__ float red[4][64];
    int c = threadIdx.x & 63;
    int part = threadIdx.x >> 6;
    int e = blockIdx.x * 64 + c;
    float s = 0.f;
    for (int d = part; d < D; d += 4) s += bln[d] * W[(size_t)d * E + e];
    red[part][c] = s; __syncthreads();
    if (part == 0) {
        float t = red[0][c] + red[1][c] + red[2][c] + red[3][c];
        if (wb) t += wb[e];
        bf[e] = t;
    }
}

// ---------------------------------------------------------------------------
// Generic tiled SGEMM: C[M,N] = A[M,K]@B[K,N] (+bias[N]) (+= if accumulate)
// M%64==0, N%64==0, K%16==0. grid (N/64, M/64), block (16,16)
// ---------------------------------------------------------------------------
__global__ __launch_bounds__(256) void sgemm_kernel(const float* __restrict__ A,
                                                    const float* __restrict__ Bm,
                                                    const float* __restrict__ bias,
                                                    float* __restrict__ C,
                                                    int M, int N, int Kd, int accumulate) {
    __shared__ float As[16][65];
    __shared__ float Bs[16][64];
    int tx = threadIdx.x, ty = threadIdx.y;
    int tid = ty * 16 + tx;
    int row0 = blockIdx.y * 64;
    int col0 = blockIdx.x * 64;
    float acc[4][4] = {};
    for (int k0 = 0; k0 < Kd; k0 += 16) {
        {
            int e = tid * 4;
            int r = e >> 4, kk = e & 15;
            float4 av = *(const float4*)(A + (size_t)(row0 + r) * Kd + k0 + kk);
            As[kk + 0][r] = av.x; As[kk + 1][r] = av.y; As[kk + 2][r] = av.z; As[kk + 3][r] = av.w;
        }
        {
            int e = tid * 4;
            int kk = e >> 6, c = e & 63;
            *(float4*)&Bs[kk][c] = *(const float4*)(Bm + (size_t)(k0 + kk) * N + col0 + c);
        }
        __syncthreads();
        #pragma unroll
        for (int kk = 0; kk < 16; ++kk) {
            float a[4], b[4];
            #pragma unroll
            for (int i = 0; i < 4; ++i) a[i] = As[kk][ty + 16 * i];
            #pragma unroll
            for (int j = 0; j < 4; ++j) b[j] = Bs[kk][tx + 16 * j];
            #pragma unroll
            for (int i = 0; i < 4; ++i)
                #pragma unroll
                for (int j = 0; j < 4; ++j)
                    acc[i][j] += a[i] * b[j];
        }
        __syncthreads();
    }
    #pragma unroll
    for (int i = 0; i < 4; ++i) {
        int r = row0 + ty + 16 * i;
        #pragma unroll
        for (int j = 0; j < 4; ++j) {
            int c = col0 + tx + 16 * j;
            float v = acc[i][j];
            if (bias) v += bias[c];
            if (accumulate) C[(size_t)r * N + c] += v;
            else C[(size_t)r * N + c] = v;
        }
    }
}

// ---------------------------------------------------------------------------
// pack s (fp32 [rows][E]) -> sF bf16 fragment order [rows/16][8][64][8]
//   sF[tile][kc][lane][j] = s[tile*16 + (lane&15)][kc*32 + (lane>>4)*8 + j]
// ---------------------------------------------------------------------------
__global__ __launch_bounds__(256) void pack_s_kernel(const float* __restrict__ s,
                                                     unsigned short* __restrict__ sF,
                                                     int rows) {
    int idx = blockIdx.x * 256 + threadIdx.x;
    int total = (rows / 16) * 8 * 64;
    if (idx >= total) return;
    int lane = idx & 63, kc = (idx >> 6) & 7, tile = idx >> 9;
    int row = tile * 16 + (lane & 15);
    int e = kc * 32 + (lane >> 4) * 8;
    const float* src = s + (size_t)row * E_ + e;
    float4 x = *(const float4*)src;
    float4 y = *(const float4*)(src + 4);
    unsigned short out[8] = { f2bf(x.x), f2bf(x.y), f2bf(x.z), f2bf(x.w),
                              f2bf(y.x), f2bf(y.y), f2bf(y.z), f2bf(y.w) };
    *reinterpret_cast<uint4*>(sF + (size_t)idx * 8) = *reinterpret_cast<uint4*>(out);
}

// ---------------------------------------------------------------------------
// pack M_k = t[k,e]*W3[e,j] + W1[e,j]  -> bf16 B-fragment order
//   MF[bk][nt][kc][lane][j] = M[kc*32 + (lane>>4)*8 + j][nt*16 + (lane&15)]
// total threads = B*K*16*8*64
// ---------------------------------------------------------------------------
__global__ __launch_bounds__(256) void pack_M_kernel(const float* __restrict__ tP,
                                                     const float* __restrict__ W3,
                                                     const float* __restrict__ W1,
                                                     unsigned short* __restrict__ MF) {
    int idx = blockIdx.x * 256 + threadIdx.x;
    int lane = idx & 63;
    int kc = (idx >> 6) & 7;
    int nt = (idx >> 9) & 15;
    int bk = idx >> 13;
    int n = nt * 16 + (lane & 15);
    int e0 = kc * 32 + (lane >> 4) * 8;
    unsigned short out[8];
    #pragma unroll
    for (int j = 0; j < 8; ++j) {
        int e = e0 + j;
        float v = tP[(size_t)bk * E_ + e] * W3[(size_t)e * E_ + n] + W1[(size_t)e * E_ + n];
        out[j] = f2bf(v);
    }
    *reinterpret_cast<uint4*>(MF + (size_t)idx * 8) = *reinterpret_cast<uint4*>(out);
}

// ---------------------------------------------------------------------------
// Cross + edge via MFMA bf16. grid (S/64, K, B), block 256 (4 waves).
// Wave w computes rows 0..63 x cols [64w, 64w+64) of z = sF @ M_k, then
// epilogue: z + c2 -> gelu -> dot m2 -> cross-wave reduce -> softsign*mask.
// ---------------------------------------------------------------------------
__global__ __launch_bounds__(256) void cross_mfma_kernel(
    const unsigned short* __restrict__ sF,  // [B*S/16][8][64][8]
    const unsigned short* __restrict__ MF,  // [B*K][16][8][64][8]
    const float* __restrict__ c2P,          // [B*K][E]
    const float* __restrict__ m2w, const float* __restrict__ m2b,
    const float* __restrict__ mask, float* __restrict__ outE, int S)
{
    int s0 = blockIdx.x * 64;
    int k  = blockIdx.y;
    int b  = blockIdx.z;
    int tid = threadIdx.x;
    int w = tid >> 6, lane = tid & 63;
    int quad = lane >> 4, n16 = lane & 15;

    const unsigned short* aBase = sF + (size_t)(b * (S / 16) + (s0 >> 4)) * 4096;
    const unsigned short* bBase = MF + ((size_t)(b * K_ + k) * 16 + w * 4) * 4096;

    f32x4 acc[4][4];
    #pragma unroll
    for (int mt = 0; mt < 4; ++mt)
        #pragma unroll
        for (int nt = 0; nt < 4; ++nt)
            acc[mt][nt] = (f32x4){0.f, 0.f, 0.f, 0.f};

    #pragma unroll
    for (int kc = 0; kc < 8; ++kc) {
        bf16x8 af[4], bfr[4];
        #pragma unroll
        for (int mt = 0; mt < 4; ++mt)
            af[mt] = *reinterpret_cast<const bf16x8*>(aBase + (size_t)mt * 4096 + kc * 512 + lane * 8);
        #pragma unroll
        for (int nt = 0; nt < 4; ++nt)
            bfr[nt] = *reinterpret_cast<const bf16x8*>(bBase + (size_t)nt * 4096 + kc * 512 + lane * 8);
        #pragma unroll
        for (int mt = 0; mt < 4; ++mt)
            #pragma unroll
            for (int nt = 0; nt < 4; ++nt)
                acc[mt][nt] = __builtin_amdgcn_mfma_f32_16x16x32_bf16(af[mt], bfr[nt], acc[mt][nt], 0, 0, 0);
    }

    // epilogue
    const float* c2v = c2P + (size_t)(b * K_ + k) * E_;
    float c2r[4], m2r[4];
    #pragma unroll
    for (int nt = 0; nt < 4; ++nt) {
        int col = w * 64 + nt * 16 + n16;
        c2r[nt] = c2v[col];
        m2r[nt] = m2w[col];
    }
    __shared__ float pPart[4][64];
    #pragma unroll
    for (int mt = 0; mt < 4; ++mt) {
        #pragma unroll
        for (int r = 0; r < 4; ++r) {
            float p = 0.f;
            #pragma unroll
            for (int nt = 0; nt < 4; ++nt) {
                float z = acc[mt][nt][r] + c2r[nt];
                float h = 0.5f * z * (1.0f + erff(z * 0.70710678118654752f));
                p += h * m2r[nt];
            }
            p += __shfl_xor(p, 1, 64);
            p += __shfl_xor(p, 2, 64);
            p += __shfl_xor(p, 4, 64);
            p += __shfl_xor(p, 8, 64);
            if (n16 == 0) pPart[w][mt * 16 + quad * 4 + r] = p;
        }
    }
    __syncthreads();
    if (tid < 64) {
        float e = pPart[0][tid] + pPart[1][tid] + pPart[2][tid] + pPart[3][tid] + m2b[0];
        e = e / (1.0f + fabsf(e));
        int srow = s0 + tid;
        e *= mask[(size_t)b * S + srow];
        outE[((size_t)b * S + srow) * K_ + k] = e;
    }
}

// ---------------------------------------------------------------------------
// rowsum[b*K+k] = sum_s E[b,s,k]
// ---------------------------------------------------------------------------
__global__ __launch_bounds__(256) void rowsum_kernel(const float* __restrict__ E,
                                                     float* __restrict__ out, int S) {
    __shared__ float red[256];
    int idx = blockIdx.x; int b = idx >> 6; int k = idx & 63;
    int tid = threadIdx.x;
    float s = 0.f;
    for (int ss = tid; ss < S; ss += 256) s += E[((size_t)b * S + ss) * K_ + k];
    red[tid] = s; __syncthreads();
    for (int off = 128; off > 0; off >>= 1) { if (tid < off) red[tid] += red[tid + off]; __syncthreads(); }
    if (tid == 0) out[idx] = red[0];
}

// ---------------------------------------------------------------------------
// Partial einsums (no atomics): per s-chunk of 128:
//   PG[chunk][b][k][d] = sum_s E[b,s,k]*Xh[b,s,d]; PR likewise with Xr.
// grid (S/128, D/64, B), block (16,16)
// ---------------------------------------------------------------------------
__global__ __launch_bounds__(256) void einsum_part_kernel(
    const float* __restrict__ Ee,  const float* __restrict__ Xh,
    const float* __restrict__ Xr, float* __restrict__ PG,
    float* __restrict__ PR, int S)
{
    __shared__ float Es[64][68];
    __shared__ float Hs[64][68];
    __shared__ float Rs[64][68];
    int tx = threadIdx.x, ty = threadIdx.y;
    int tid = ty * 16 + tx;
    int d0 = blockIdx.y * 64;
    int b  = blockIdx.z;
    int sStart = blockIdx.x * 128;
    float accG[4][4] = {}, accR[4][4] = {};
    int ss = tid >> 2, kk0 = (tid & 3) * 16;
    for (int s1 = sStart; s1 < sStart + 128; s1 += 64) {
        #pragma unroll
        for (int q = 0; q < 4; ++q)
            *(float4*)&Es[ss][kk0 + q * 4] = *(const float4*)(Ee + ((size_t)b * S + s1 + ss) * K_ + kk0 + q * 4);
        #pragma unroll
        for (int q = 0; q < 4; ++q) {
            *(float4*)&Hs[ss][kk0 + q * 4] = *(const float4*)(Xh + ((size_t)b * S + s1 + ss) * D_ + d0 + kk0 + q * 4);
            *(float4*)&Rs[ss][kk0 + q * 4] = *(const float4*)(Xr + ((size_t)b * S + s1 + ss) * D_ + d0 + kk0 + q * 4);
        }
        __syncthreads();
        for (int s2 = 0; s2 < 64; ++s2) {
            float ev[4], hv[4], rv[4];
            #pragma unroll
            for (int i = 0; i < 4; ++i) ev[i] = Es[s2][ty + 16 * i];
            #pragma unroll
            for (int j = 0; j < 4; ++j) { hv[j] = Hs[s2][tx + 16 * j]; rv[j] = Rs[s2][tx + 16 * j]; }
            #pragma unroll
            for (int i = 0; i < 4; ++i)
                #pragma unroll
                for (int j = 0; j < 4; ++j) {
                    accG[i][j] += ev[i] * hv[j];
                    accR[i][j] += ev[i] * rv[j];
                }
        }
        __syncthreads();
    }
    #pragma unroll
    for (int i = 0; i < 4; ++i)
        #pragma unroll
        for (int j = 0; j < 4; ++j) {
            size_t o = (((size_t)blockIdx.x * B_ + b) * K_ + ty + 16 * i) * D_ + d0 + tx + 16 * j;
            PG[o] = accG[i][j];
            PR[o] = accR[i][j];
        }
}

// ---------------------------------------------------------------------------
// Reduce partials: Gt = sum PtG, Gi = sum PiG, Racc = sum PtR + sum PiR
// ---------------------------------------------------------------------------
__global__ __launch_bounds__(256) void reduce_parts_kernel(
    const float* __restrict__ PtG, const float* __restrict__ PtR,
    const float* __restrict__ PiG, const float* __restrict__ PiR,
    float* __restrict__ Gt, float* __restrict__ Gi, float* __restrict__ Racc)
{
    const int BKD = B_ * K_ * D_;
    int idx = blockIdx.x * 256 + threadIdx.x;
    if (idx >= BKD) return;
    float gt = 0.f, gi = 0.f, r = 0.f;
    #pragma unroll 4
    for (int c = 0; c < 16; ++c) { gt += PtG[(size_t)c * BKD + idx]; r += PtR[(size_t)c * BKD + idx]; }
    #pragma unroll 4
    for (int c = 0; c < 8; ++c)  { gi += PiG[(size_t)c * BKD + idx]; r += PiR[(size_t)c * BKD + idx]; }
    Gt[idx] = gt; Gi[idx] = gi; Racc[idx] = r;
}

// ---------------------------------------------------------------------------
// Final LN: grid 256 blocks; idx<128 -> latent_state row, else latent_value row
// ---------------------------------------------------------------------------
__global__ __launch_bounds__(256) void final_ln_kernel(
    const float* __restrict__ stateTmp, const float* __restrict__ Racc,
    const float* __restrict__ rs_t, const float* __restrict__ rs_i,
    const float* __restrict__ b_tspf, const float* __restrict__ b_ispf,
    const float* __restrict__ state_init, const float* __restrict__ value_init,
    const float* __restrict__ stn_g, const float* __restrict__ stn_b,
    const float* __restrict__ vn_g, const float* __restrict__ vn_b,
    float* __restrict__ outState, float* __restrict__ outValue)
{
    __shared__ float pre[D_];
    __shared__ float red[256];
    int idx = blockIdx.x;
    int row = idx & 127;
    int isVal = idx >> 7;
    int tid = threadIdx.x;
    if (!isVal) {
        float rt = rs_t[row], ri = rs_i[row];
        for (int d = tid; d < D_; d += 256)
            pre[d] = stateTmp[(size_t)row * D_ + d] + rt * b_tspf[d] + ri * b_ispf[d]
                   + state_init[(size_t)row * D_ + d];
    } else {
        for (int d = tid; d < D_; d += 256)
            pre[d] = Racc[(size_t)row * D_ + d] + value_init[(size_t)row * D_ + d];
    }
    __syncthreads();
    float s = 0.f;
    for (int d = tid; d < D_; d += 256) s += pre[d];
    red[tid] = s; __syncthreads();
    for (int off = 128; off > 0; off >>= 1) { if (tid < off) red[tid] += red[tid + off]; __syncthreads(); }
    float mu = red[0] / (float)D_;
    __syncthreads();
    float v = 0.f;
    for (int d = tid; d < D_; d += 256) { float t = pre[d] - mu; v += t * t; }
    red[tid] = v; __syncthreads();
    for (int off = 128; off > 0; off >>= 1) { if (tid < off) red[tid] += red[tid + off]; __syncthreads(); }
    float rstd = rsqrtf(red[0] / (float)D_ + EPS_LN);
    const float* g  = isVal ? vn_g : stn_g;
    const float* bb = isVal ? vn_b : stn_b;
    float* o = (isVal ? outValue : outState) + (size_t)row * D_;
    for (int d = tid; d < D_; d += 256) o[d] = (pre[d] - mu) * rstd * g[d] + bb[d];
}

// ---------------------------------------------------------------------------
extern "C" void kernel_launch(void* const* d_in, const int* in_sizes, int n_in,
                              void* d_out, int out_size, void* d_ws, size_t ws_size,
                              hipStream_t stream) {
    const float* text_values  = (const float*)d_in[0];
    const float* image_values = (const float*)d_in[1];
    const float* lstate_init  = (const float*)d_in[2];
    const float* lvalue_init  = (const float*)d_in[3];
    const float* text_mask    = (const float*)d_in[4];
    const float* image_mask   = (const float*)d_in[5];
    const float* t_sn_g = (const float*)d_in[6];
    const float* t_sn_b = (const float*)d_in[7];
    const float* t_tn_g = (const float*)d_in[8];
    const float* t_tn_b = (const float*)d_in[9];
    const float* t_su_w = (const float*)d_in[10];
    const float* t_su_b = (const float*)d_in[11];
    const float* t_tp_w = (const float*)d_in[12];
    const float* t_tp_b = (const float*)d_in[13];
    const float* t_m1_w = (const float*)d_in[14];
    const float* t_m1_b = (const float*)d_in[15];
    const float* t_m2_w = (const float*)d_in[16];
    const float* t_m2_b = (const float*)d_in[17];
    const float* i_sn_g = (const float*)d_in[18];
    const float* i_sn_b = (const float*)d_in[19];
    const float* i_tn_g = (const float*)d_in[20];
    const float* i_tn_b = (const float*)d_in[21];
    const float* i_su_w = (const float*)d_in[22];
    const float* i_su_b = (const float*)d_in[23];
    const float* i_tp_w = (const float*)d_in[24];
    const float* i_tp_b = (const float*)d_in[25];
    const float* i_m1_w = (const float*)d_in[26];
    const float* i_m1_b = (const float*)d_in[27];
    const float* i_m2_w = (const float*)d_in[28];
    const float* i_m2_b = (const float*)d_in[29];
    const float* tsn_g = (const float*)d_in[30];
    const float* tsn_b = (const float*)d_in[31];
    const float* isn_g = (const float*)d_in[32];
    const float* isn_b = (const float*)d_in[33];
    const float* stn_g = (const float*)d_in[34];
    const float* stn_b = (const float*)d_in[35];
    const float* vn_g  = (const float*)d_in[36];
    const float* vn_b  = (const float*)d_in[37];
    const float* tsp_w = (const float*)d_in[38];
    const float* tsp_b = (const float*)d_in[39];
    const float* isp_w = (const float*)d_in[40];
    const float* isp_b = (const float*)d_in[41];

    float* ws = (float*)d_ws;
    size_t o = 0;
    float* xhat_text  = ws + o; o += (size_t)B_ * ST_ * D_;
    float* xhat_image = ws + o; o += (size_t)B_ * SI_ * D_;
    float* xhat_lat   = ws + o; o += (size_t)B_ * K_  * D_;
    float* W_su_t = ws + o; o += (size_t)D_ * E_;
    float* W_su_i = ws + o; o += (size_t)D_ * E_;
    float* W_tp_t = ws + o; o += (size_t)D_ * E_;
    float* W_tp_i = ws + o; o += (size_t)D_ * E_;
    float* W_tspf = ws + o; o += (size_t)D_ * D_;
    float* W_ispf = ws + o; o += (size_t)D_ * D_;
    float* b_su_t = ws + o; o += E_;
    float* b_su_i = ws + o; o += E_;
    float* b_tp_t = ws + o; o += E_;
    float* b_tp_i = ws + o; o += E_;
    float* b_tspf = ws + o; o += D_;
    float* b_ispf = ws + o; o += D_;
    float* s_text  = ws + o; o += (size_t)B_ * ST_ * E_;
    float* s_image = ws + o; o += (size_t)B_ * SI_ * E_;
    float* t_t  = ws + o; o += (size_t)B_ * K_ * E_;
    float* t_i  = ws + o; o += (size_t)B_ * K_ * E_;
    float* c2_t = ws + o; o += (size_t)B_ * K_ * E_;
    float* c2_i = ws + o; o += (size_t)B_ * K_ * E_;
    unsigned short* sF_text = (unsigned short*)(ws + o); o += (size_t)B_ * ST_ * E_ / 2;
    unsigned short* sF_img  = (unsigned short*)(ws + o); o += (size_t)B_ * SI_ * E_ / 2;
    unsigned short* MF_t = (unsigned short*)(ws + o); o += (size_t)B_ * K_ * E_ * E_ / 2;
    unsigned short* MF_i = (unsigned short*)(ws + o); o += (size_t)B_ * K_ * E_ * E_ / 2;
    const int BKD = B_ * K_ * D_;
    float* PtG = ws + o; o += (size_t)16 * BKD;
    float* PtR = ws + o; o += (size_t)16 * BKD;
    float* PiG = ws + o; o += (size_t)8 * BKD;
    float* PiR = ws + o; o += (size_t)8 * BKD;
    float* Gt   = ws + o; o += BKD;
    float* Gi   = ws + o; o += BKD;
    float* Racc = ws + o; o += BKD;
    float* rs_t = ws + o; o += B_ * K_;
    float* rs_i = ws + o; o += B_ * K_;
    float* state_tmp = ws + o; o += BKD;

    float* outState = (float*)d_out;                       // [B,K,D]
    float* outValue = (float*)d_out + (size_t)B_ * K_ * D_;
    float* t2l = (float*)d_out + 2 * (size_t)B_ * K_ * D_;             // [B,ST,K]
    float* i2l = t2l + (size_t)B_ * ST_ * K_;                          // [B,SI,K]

    // --- fold weights/biases ---
    fold_w_kernel<<<(D_ * E_ + 255) / 256, 256, 0, stream>>>(t_sn_g, t_su_w, W_su_t, D_, E_);
    fold_w_kernel<<<(D_ * E_ + 255) / 256, 256, 0, stream>>>(i_sn_g, i_su_w, W_su_i, D_, E_);
    fold_w_kernel<<<(D_ * E_ + 255) / 256, 256, 0, stream>>>(t_tn_g, t_tp_w, W_tp_t, D_, E_);
    fold_w_kernel<<<(D_ * E_ + 255) / 256, 256, 0, stream>>>(i_tn_g, i_tp_w, W_tp_i, D_, E_);
    fold_w_kernel<<<(D_ * D_ + 255) / 256, 256, 0, stream>>>(tsn_g, tsp_w, W_tspf, D_, D_);
    fold_w_kernel<<<(D_ * D_ + 255) / 256, 256, 0, stream>>>(isn_g, isp_w, W_ispf, D_, D_);
    fold_b_kernel<<<E_ / 64, 256, 0, stream>>>(t_sn_b, t_su_w, t_su_b, b_su_t, D_, E_);
    fold_b_kernel<<<E_ / 64, 256, 0, stream>>>(i_sn_b, i_su_w, i_su_b, b_su_i, D_, E_);
    fold_b_kernel<<<E_ / 64, 256, 0, stream>>>(t_tn_b, t_tp_w, t_tp_b, b_tp_t, D_, E_);
    fold_b_kernel<<<E_ / 64, 256, 0, stream>>>(i_tn_b, i_tp_w, i_tp_b, b_tp_i, D_, E_);
    fold_b_kernel<<<D_ / 64, 256, 0, stream>>>(tsn_b, tsp_w, tsp_b, b_tspf, D_, D_);
    fold_b_kernel<<<D_ / 64, 256, 0, stream>>>(isn_b, isp_w, isp_b, b_ispf, D_, D_);

    // --- xhat ---
    ln_xhat_kernel<<<B_ * ST_, 256, 0, stream>>>(text_values, xhat_text);
    ln_xhat_kernel<<<B_ * SI_, 256, 0, stream>>>(image_values, xhat_image);
    ln_xhat_kernel<<<B_ * K_,  256, 0, stream>>>(lvalue_init, xhat_lat);

    dim3 blk16(16, 16);
    // s projections: [B*S,768]@[768,256]
    sgemm_kernel<<<dim3(E_ / 64, B_ * ST_ / 64), blk16, 0, stream>>>(xhat_text, W_su_t, b_su_t, s_text, B_ * ST_, E_, D_, 0);
    sgemm_kernel<<<dim3(E_ / 64, B_ * SI_ / 64), blk16, 0, stream>>>(xhat_image, W_su_i, b_su_i, s_image, B_ * SI_, E_, D_, 0);
    // t projections: [B*K,768]@[768,256]
    sgemm_kernel<<<dim3(E_ / 64, B_ * K_ / 64), blk16, 0, stream>>>(xhat_lat, W_tp_t, b_tp_t, t_t, B_ * K_, E_, D_, 0);
    sgemm_kernel<<<dim3(E_ / 64, B_ * K_ / 64), blk16, 0, stream>>>(xhat_lat, W_tp_i, b_tp_i, t_i, B_ * K_, E_, D_, 0);
    // c2 = t @ W2 + m1_b
    sgemm_kernel<<<dim3(E_ / 64, B_ * K_ / 64), blk16, 0, stream>>>(t_t, t_m1_w + (size_t)E_ * E_, t_m1_b, c2_t, B_ * K_, E_, E_, 0);
    sgemm_kernel<<<dim3(E_ / 64, B_ * K_ / 64), blk16, 0, stream>>>(t_i, i_m1_w + (size_t)E_ * E_, i_m1_b, c2_i, B_ * K_, E_, E_, 0);

    // --- pack fragments ---
    pack_s_kernel<<<((B_ * ST_ / 16) * 8 * 64 + 255) / 256, 256, 0, stream>>>(s_text, sF_text, B_ * ST_);
    pack_s_kernel<<<((B_ * SI_ / 16) * 8 * 64 + 255) / 256, 256, 0, stream>>>(s_image, sF_img, B_ * SI_);
    pack_M_kernel<<<(B_ * K_ * 16 * 8 * 64) / 256, 256, 0, stream>>>(t_t, t_m1_w + 2 * (size_t)E_ * E_, t_m1_w, MF_t);
    pack_M_kernel<<<(B_ * K_ * 16 * 8 * 64) / 256, 256, 0, stream>>>(t_i, i_m1_w + 2 * (size_t)E_ * E_, i_m1_w, MF_i);

    // --- cross + edge via MFMA ---
    cross_mfma_kernel<<<dim3(ST_ / 64, K_, B_), 256, 0, stream>>>(
        sF_text, MF_t, c2_t, t_m2_w, t_m2_b, text_mask, t2l, ST_);
    cross_mfma_kernel<<<dim3(SI_ / 64, K_, B_), 256, 0, stream>>>(
        sF_img, MF_i, c2_i, i_m2_w, i_m2_b, image_mask, i2l, SI_);

    // --- aggregation ---
    rowsum_kernel<<<B_ * K_, 256, 0, stream>>>(t2l, rs_t, ST_);
    rowsum_kernel<<<B_ * K_, 256, 0, stream>>>(i2l, rs_i, SI_);
    einsum_part_kernel<<<dim3(ST_ / 128, D_ / 64, B_), blk16, 0, stream>>>(t2l, xhat_text, text_values, PtG, PtR, ST_);
    einsum_part_kernel<<<dim3(SI_ / 128, D_ / 64, B_), blk16, 0, stream>>>(i2l, xhat_image, image_values, PiG, PiR, SI_);
    reduce_parts_kernel<<<(BKD + 255) / 256, 256, 0, stream>>>(PtG, PtR, PiG, PiR, Gt, Gi, Racc);

    // state_tmp = Gt@W_tspf + Gi@W_ispf   ([128,768]@[768,768])
    sgemm_kernel<<<dim3(D_ / 64, B_ * K_ / 64), blk16, 0, stream>>>(Gt, W_tspf, nullptr, state_tmp, B_ * K_, D_, D_, 0);
    sgemm_kernel<<<dim3(D_ / 64, B_ * K_ / 64), blk16, 0, stream>>>(Gi, W_ispf, nullptr, state_tmp, B_ * K_, D_, D_, 1);

    // --- final LN ---
    final_ln_kernel<<<2 * B_ * K_, 256, 0, stream>>>(
        state_tmp, Racc, rs_t, rs_i, b_tspf, b_ispf,
        lstate_init, lvalue_init, stn_g, stn_b, vn_g, vn_b, outState, outValue);
}

// Round 3
// 1062.714 us; speedup vs baseline: 2.8196x; 1.0145x over previous
//
#include <hip/hip_runtime.h>
#include <math.h>

#define EPS_LN 1e-5f

// Problem dims (fixed by harness)
#define B_  2
#define ST_ 2048
#define SI_ 1024
#define K_  64
#define D_  768
#define E_  256

typedef __bf16 bf16x8 __attribute__((ext_vector_type(8)));
typedef float  f32x4  __attribute__((ext_vector_type(4)));
typedef unsigned short ushort_t;

__device__ inline ushort_t f2bf(float x) {
    unsigned int u = __float_as_uint(x);
    unsigned int r = (u + 0x7FFFu + ((u >> 16) & 1u)) >> 16;
    return (ushort_t)r;
}

// A&S 7.1.26 erf approximation, |err| <= 1.5e-7
__device__ inline float erf_fast(float x) {
    float ax = fabsf(x);
    float t = __builtin_amdgcn_rcpf(fmaf(0.3275911f, ax, 1.0f));
    float poly = t * (0.254829592f + t * (-0.284496736f + t * (1.421413741f +
                 t * (-1.453152027f + t * 1.061405429f))));
    float y = 1.0f - poly * __expf(-ax * ax);
    return copysignf(y, x);
}
__device__ inline float gelu_fast(float z) {
    return 0.5f * z * (1.0f + erf_fast(z * 0.70710678118654752f));
}

// ---------------------------------------------------------------------------
// LN xhat: one block per row
// ---------------------------------------------------------------------------
__global__ __launch_bounds__(256) void ln_xhat_kernel(const float* __restrict__ x,
                                                      float* __restrict__ xhat) {
    int row = blockIdx.x;
    const float* xr = x + (size_t)row * D_;
    float* xo = xhat + (size_t)row * D_;
    int tid = threadIdx.x;
    __shared__ float red[256];
    float s = 0.f;
    for (int d = tid; d < D_; d += 256) s += xr[d];
    red[tid] = s; __syncthreads();
    for (int off = 128; off > 0; off >>= 1) { if (tid < off) red[tid] += red[tid + off]; __syncthreads(); }
    float mu = red[0] / (float)D_;
    __syncthreads();
    float v = 0.f;
    for (int d = tid; d < D_; d += 256) { float t = xr[d] - mu; v += t * t; }
    red[tid] = v; __syncthreads();
    for (int off = 128; off > 0; off >>= 1) { if (tid < off) red[tid] += red[tid + off]; __syncthreads(); }
    float rstd = rsqrtf(red[0] / (float)D_ + EPS_LN);
    for (int d = tid; d < D_; d += 256) xo[d] = (xr[d] - mu) * rstd;
}

// bias folding: bf[e] = sum_d bln[d]*W[d,e] + (wb ? wb[e] : 0). grid = E/64
__global__ __launch_bounds__(256) void fold_b_kernel(const float* __restrict__ bln, const float* __restrict__ W,
                              const float* __restrict__ wb, float* __restrict__ bf, int D, int E) {
    __shared__ float red[4][64];
    int c = threadIdx.x & 63;
    int part = threadIdx.x >> 6;
    int e = blockIdx.x * 64 + c;
    float s = 0.f;
    for (int d = part; d < D; d += 4) s += bln[d] * W[(size_t)d * E + e];
    red[part][c] = s; __syncthreads();
    if (part == 0) {
        float t = red[0][c] + red[1][c] + red[2][c] + red[3][c];
        if (wb) t += wb[e];
        bf[e] = t;
    }
}

// ---------------------------------------------------------------------------
// Tiled SGEMM (fp32, used for small GEMMs): C = A@((rowScale?)B) (+bias)(+=)
// grid (N/64, M/64), block (16,16)
// ---------------------------------------------------------------------------
__global__ __launch_bounds__(256) void sgemm_kernel(const float* __restrict__ A,
                                                    const float* __restrict__ Bm,
                                                    const float* __restrict__ rowScale,
                                                    const float* __restrict__ bias,
                                                    float* __restrict__ C,
                                                    int M, int N, int Kd, int accumulate) {
    __shared__ float As[16][65];
    __shared__ float Bs[16][64];
    int tx = threadIdx.x, ty = threadIdx.y;
    int tid = ty * 16 + tx;
    int row0 = blockIdx.y * 64;
    int col0 = blockIdx.x * 64;
    float acc[4][4] = {};
    for (int k0 = 0; k0 < Kd; k0 += 16) {
        {
            int e = tid * 4;
            int r = e >> 4, kk = e & 15;
            float4 av = *(const float4*)(A + (size_t)(row0 + r) * Kd + k0 + kk);
            As[kk + 0][r] = av.x; As[kk + 1][r] = av.y; As[kk + 2][r] = av.z; As[kk + 3][r] = av.w;
        }
        {
            int e = tid * 4;
            int kk = e >> 6, c = e & 63;
            float4 bv = *(const float4*)(Bm + (size_t)(k0 + kk) * N + col0 + c);
            float sc = rowScale ? rowScale[k0 + kk] : 1.0f;
            bv.x *= sc; bv.y *= sc; bv.z *= sc; bv.w *= sc;
            *(float4*)&Bs[kk][c] = bv;
        }
        __syncthreads();
        #pragma unroll
        for (int kk = 0; kk < 16; ++kk) {
            float a[4], b[4];
            #pragma unroll
            for (int i = 0; i < 4; ++i) a[i] = As[kk][ty + 16 * i];
            #pragma unroll
            for (int j = 0; j < 4; ++j) b[j] = Bs[kk][tx + 16 * j];
            #pragma unroll
            for (int i = 0; i < 4; ++i)
                #pragma unroll
                for (int j = 0; j < 4; ++j)
                    acc[i][j] += a[i] * b[j];
        }
        __syncthreads();
    }
    #pragma unroll
    for (int i = 0; i < 4; ++i) {
        int r = row0 + ty + 16 * i;
        #pragma unroll
        for (int j = 0; j < 4; ++j) {
            int c = col0 + tx + 16 * j;
            float v = acc[i][j];
            if (bias) v += bias[c];
            if (accumulate) C[(size_t)r * N + c] += v;
            else C[(size_t)r * N + c] = v;
        }
    }
}

// ---------------------------------------------------------------------------
// packA: fp32 [rows][Kd] -> bf16 A-frags [rows/16][Kd/32][64][8]
//   out[tile][c][lane][j] = x[tile*16+(lane&15)][c*32+(lane>>4)*8+j]
// ---------------------------------------------------------------------------
__global__ __launch_bounds__(256) void packA_kernel(const float* __restrict__ x,
                                                    ushort_t* __restrict__ out,
                                                    int rows, int Kd) {
    int idx = blockIdx.x * 256 + threadIdx.x;
    int nChunk = Kd >> 5;
    int total = (rows >> 4) * nChunk * 64;
    if (idx >= total) return;
    int lane = idx & 63;
    int c = (idx >> 6) % nChunk;
    int tile = idx / (64 * nChunk);
    int row = tile * 16 + (lane & 15);
    int col = c * 32 + (lane >> 4) * 8;
    const float* src = x + (size_t)row * Kd + col;
    float4 a = *(const float4*)src;
    float4 b = *(const float4*)(src + 4);
    ushort_t o[8] = { f2bf(a.x), f2bf(a.y), f2bf(a.z), f2bf(a.w),
                      f2bf(b.x), f2bf(b.y), f2bf(b.z), f2bf(b.w) };
    *reinterpret_cast<uint4*>(out + (size_t)idx * 8) = *reinterpret_cast<uint4*>(o);
}

// ---------------------------------------------------------------------------
// packB: fp32 [Kd][N] (optional row scale g[Kd]) -> bf16 B-frags
//   out[c][ntile][lane][j] = g[k]*W[k][n], k=c*32+(lane>>4)*8+j, n=ntile*16+(lane&15)
// ---------------------------------------------------------------------------
__global__ __launch_bounds__(256) void packB_kernel(const float* __restrict__ W,
                                                    const float* __restrict__ g,
                                                    ushort_t* __restrict__ out,
                                                    int Kd, int N) {
    int idx = blockIdx.x * 256 + threadIdx.x;
    int nTile = N >> 4;
    int total = (Kd >> 5) * nTile * 64;
    if (idx >= total) return;
    int lane = idx & 63;
    int ntile = (idx >> 6) % nTile;
    int c = idx / (64 * nTile);
    int n = ntile * 16 + (lane & 15);
    int k0 = c * 32 + (lane >> 4) * 8;
    ushort_t o[8];
    #pragma unroll
    for (int j = 0; j < 8; ++j) {
        int k = k0 + j;
        float v = W[(size_t)k * N + n];
        if (g) v *= g[k];
        o[j] = f2bf(v);
    }
    *reinterpret_cast<uint4*>(out + (size_t)idx * 8) = *reinterpret_cast<uint4*>(o);
}

// ---------------------------------------------------------------------------
// s-projection via MFMA: s = xhat@Wf + bias, output directly in sF A-frag
// layout [rows/16][8][64][8]. grid rows/64, block 256 (4 waves).
// Wave w: 64 rows x cols [64w,64w+64).
// ---------------------------------------------------------------------------
__global__ __launch_bounds__(256) void sproj_mfma_kernel(
    const ushort_t* __restrict__ AF,  // [rows/16][24][64][8]
    const ushort_t* __restrict__ BF,  // [24][16][64][8]
    const float* __restrict__ bias,   // [256]
    ushort_t* __restrict__ sF,        // [rows/16][8][64][8]
    int rows)
{
    __shared__ __align__(16) ushort_t ls[4][64][72];
    int w = threadIdx.x >> 6, lane = threadIdx.x & 63;
    int quad = lane >> 4, n16 = lane & 15;
    int tile0 = blockIdx.x * 4;

    f32x4 acc[4][4];
    #pragma unroll
    for (int mt = 0; mt < 4; ++mt)
        #pragma unroll
        for (int nt = 0; nt < 4; ++nt)
            acc[mt][nt] = (f32x4){0.f, 0.f, 0.f, 0.f};

    for (int c = 0; c < 24; ++c) {
        bf16x8 af[4], bf[4];
        #pragma unroll
        for (int mt = 0; mt < 4; ++mt)
            af[mt] = *reinterpret_cast<const bf16x8*>(AF + ((size_t)(tile0 + mt) * 24 + c) * 512 + lane * 8);
        #pragma unroll
        for (int nt = 0; nt < 4; ++nt)
            bf[nt] = *reinterpret_cast<const bf16x8*>(BF + ((size_t)c * 16 + w * 4 + nt) * 512 + lane * 8);
        #pragma unroll
        for (int mt = 0; mt < 4; ++mt)
            #pragma unroll
            for (int nt = 0; nt < 4; ++nt)
                acc[mt][nt] = __builtin_amdgcn_mfma_f32_16x16x32_bf16(af[mt], bf[nt], acc[mt][nt], 0, 0, 0);
    }
    // epilogue: +bias, bf16, wave-local transpose via LDS
    #pragma unroll
    for (int mt = 0; mt < 4; ++mt)
        #pragma unroll
        for (int nt = 0; nt < 4; ++nt) {
            float bv = bias[w * 64 + nt * 16 + n16];
            #pragma unroll
            for (int r = 0; r < 4; ++r)
                ls[w][mt * 16 + quad * 4 + r][nt * 16 + n16] = f2bf(acc[mt][nt][r] + bv);
        }
    __syncthreads();
    #pragma unroll
    for (int mt = 0; mt < 4; ++mt)
        #pragma unroll
        for (int h = 0; h < 2; ++h) {
            uint4 v = *reinterpret_cast<const uint4*>(&ls[w][mt * 16 + n16][h * 32 + quad * 8]);
            *reinterpret_cast<uint4*>(sF + ((size_t)(tile0 + mt) * 8 + 2 * w + h) * 512 + lane * 8) = v;
        }
}

// ---------------------------------------------------------------------------
// pack M_k = t[k,e]*W3[e,j] + W1[e,j]  -> bf16 B-frag order
// ---------------------------------------------------------------------------
__global__ __launch_bounds__(256) void pack_M_kernel(const float* __restrict__ tP,
                                                     const float* __restrict__ W3,
                                                     const float* __restrict__ W1,
                                                     ushort_t* __restrict__ MF) {
    int idx = blockIdx.x * 256 + threadIdx.x;
    int lane = idx & 63;
    int kc = (idx >> 6) & 7;
    int nt = (idx >> 9) & 15;
    int bk = idx >> 13;
    int n = nt * 16 + (lane & 15);
    int e0 = kc * 32 + (lane >> 4) * 8;
    ushort_t out[8];
    #pragma unroll
    for (int j = 0; j < 8; ++j) {
        int e = e0 + j;
        float v = tP[(size_t)bk * E_ + e] * W3[(size_t)e * E_ + n] + W1[(size_t)e * E_ + n];
        out[j] = f2bf(v);
    }
    *reinterpret_cast<uint4*>(MF + (size_t)idx * 8) = *reinterpret_cast<uint4*>(out);
}

// ---------------------------------------------------------------------------
// Cross + edge via MFMA. grid (S/128, K, B), block 256 (4 waves).
// Wave w: 128 rows (mt=8) x cols [64w,64w+64) (nt=4).
// Epilogue: z+c2 -> gelu -> dot m2 -> reduce -> softsign*mask -> t2l + EF(bf16)
// ---------------------------------------------------------------------------
__global__ __launch_bounds__(256, 2) void cross_mfma_kernel(
    const ushort_t* __restrict__ sF,  // [B*S/16][8][64][8]
    const ushort_t* __restrict__ MF,  // [B*K][16][8][64][8]
    const float* __restrict__ c2P,    // [B*K][E]
    const float* __restrict__ m2w, const float* __restrict__ m2b,
    const float* __restrict__ mask, float* __restrict__ outE,
    ushort_t* __restrict__ EF,        // [(B*S)/32][4][64][8]
    int S)
{
    int s0 = blockIdx.x * 128;
    int k  = blockIdx.y;
    int b  = blockIdx.z;
    int tid = threadIdx.x;
    int w = tid >> 6, lane = tid & 63;
    int quad = lane >> 4, n16 = lane & 15;

    const ushort_t* aBase = sF + (size_t)(b * (S / 16) + (s0 >> 4)) * 4096;
    const ushort_t* bBase = MF + ((size_t)(b * K_ + k) * 16 + w * 4) * 4096;

    f32x4 acc[8][4];
    #pragma unroll
    for (int mt = 0; mt < 8; ++mt)
        #pragma unroll
        for (int nt = 0; nt < 4; ++nt)
            acc[mt][nt] = (f32x4){0.f, 0.f, 0.f, 0.f};

    #pragma unroll
    for (int kc = 0; kc < 8; ++kc) {
        bf16x8 bfr[4];
        #pragma unroll
        for (int nt = 0; nt < 4; ++nt)
            bfr[nt] = *reinterpret_cast<const bf16x8*>(bBase + (size_t)nt * 4096 + kc * 512 + lane * 8);
        #pragma unroll
        for (int mt = 0; mt < 8; ++mt) {
            bf16x8 af = *reinterpret_cast<const bf16x8*>(aBase + (size_t)mt * 4096 + kc * 512 + lane * 8);
            #pragma unroll
            for (int nt = 0; nt < 4; ++nt)
                acc[mt][nt] = __builtin_amdgcn_mfma_f32_16x16x32_bf16(af, bfr[nt], acc[mt][nt], 0, 0, 0);
        }
    }

    const float* c2v = c2P + (size_t)(b * K_ + k) * E_;
    float c2r[4], m2r[4];
    #pragma unroll
    for (int nt = 0; nt < 4; ++nt) {
        int col = w * 64 + nt * 16 + n16;
        c2r[nt] = c2v[col];
        m2r[nt] = m2w[col];
    }
    __shared__ float pPart[4][128];
    #pragma unroll
    for (int mt = 0; mt < 8; ++mt) {
        #pragma unroll
        for (int r = 0; r < 4; ++r) {
            float p = 0.f;
            #pragma unroll
            for (int nt = 0; nt < 4; ++nt) {
                float z = acc[mt][nt][r] + c2r[nt];
                p += gelu_fast(z) * m2r[nt];
            }
            p += __shfl_xor(p, 1, 64);
            p += __shfl_xor(p, 2, 64);
            p += __shfl_xor(p, 4, 64);
            p += __shfl_xor(p, 8, 64);
            if (n16 == 0) pPart[w][mt * 16 + quad * 4 + r] = p;
        }
    }
    __syncthreads();
    if (tid < 128) {
        float e = pPart[0][tid] + pPart[1][tid] + pPart[2][tid] + pPart[3][tid] + m2b[0];
        e = e / (1.0f + fabsf(e));
        int srow = s0 + tid;
        e *= mask[(size_t)b * S + srow];
        outE[((size_t)b * S + srow) * K_ + k] = e;
        // EF[c][mt][lane'][j]: c=(b*S+srow)/32, mt=k/16, lane'=(k&15)+((srow>>3)&3)*16, j=srow&7
        int c = (b * S + srow) >> 5;
        int mt = k >> 4;
        int lp = (k & 15) + (((srow >> 3) & 3) << 4);
        EF[(((size_t)c * 4 + mt) * 64 + lp) * 8 + (srow & 7)] = f2bf(e);
    }
}

// ---------------------------------------------------------------------------
// rowsum[b*K+k] = sum_s E[b,s,k]
// ---------------------------------------------------------------------------
__global__ __launch_bounds__(256) void rowsum_kernel(const float* __restrict__ E,
                                                     float* __restrict__ out, int S) {
    __shared__ float red[256];
    int idx = blockIdx.x; int b = idx >> 6; int k = idx & 63;
    int tid = threadIdx.x;
    float s = 0.f;
    for (int ss = tid; ss < S; ss += 256) s += E[((size_t)b * S + ss) * K_ + k];
    red[tid] = s; __syncthreads();
    for (int off = 128; off > 0; off >>= 1) { if (tid < off) red[tid] += red[tid + off]; __syncthreads(); }
    if (tid == 0) out[idx] = red[0];
}

// ---------------------------------------------------------------------------
// einsum via MFMA: PG[y][b][k][d] = sum_{s in block y} e[s,k]*xhat[s,d]
//                  PR likewise with raw x. grid (N/256=3, 8, B), block 256.
// ---------------------------------------------------------------------------
__global__ __launch_bounds__(256, 2) void einsum_mfma_kernel(
    const ushort_t* __restrict__ EF,   // [(B*S)/32][4][64][8]
    const ushort_t* __restrict__ XhF,  // [(B*S)/32][48][64][8]
    const ushort_t* __restrict__ XrF,
    float* __restrict__ PG, float* __restrict__ PR,  // [8][B][64][768]
    int S, int chunksPerBlock)
{
    int w = threadIdx.x >> 6, lane = threadIdx.x & 63;
    int quad = lane >> 4, n16 = lane & 15;
    int b = blockIdx.z, y = blockIdx.y;
    int nt0 = blockIdx.x * 16 + w * 4;  // ntile base (48 total)
    size_t cb = (size_t)(b * S) / 32 + (size_t)y * chunksPerBlock;

    f32x4 aG[4][4], aR[4][4];
    #pragma unroll
    for (int mt = 0; mt < 4; ++mt)
        #pragma unroll
        for (int nt = 0; nt < 4; ++nt) {
            aG[mt][nt] = (f32x4){0.f, 0.f, 0.f, 0.f};
            aR[mt][nt] = (f32x4){0.f, 0.f, 0.f, 0.f};
        }

    for (int cc = 0; cc < chunksPerBlock; ++cc) {
        size_t c = cb + cc;
        bf16x8 af[4], bh[4], bx[4];
        #pragma unroll
        for (int mt = 0; mt < 4; ++mt)
            af[mt] = *reinterpret_cast<const bf16x8*>(EF + ((c * 4 + mt) * 64 + lane) * 8);
        #pragma unroll
        for (int nt = 0; nt < 4; ++nt) {
            bh[nt] = *reinterpret_cast<const bf16x8*>(XhF + ((c * 48 + nt0 + nt) * 64 + lane) * 8);
            bx[nt] = *reinterpret_cast<const bf16x8*>(XrF + ((c * 48 + nt0 + nt) * 64 + lane) * 8);
        }
        #pragma unroll
        for (int mt = 0; mt < 4; ++mt)
            #pragma unroll
            for (int nt = 0; nt < 4; ++nt) {
                aG[mt][nt] = __builtin_amdgcn_mfma_f32_16x16x32_bf16(af[mt], bh[nt], aG[mt][nt], 0, 0, 0);
                aR[mt][nt] = __builtin_amdgcn_mfma_f32_16x16x32_bf16(af[mt], bx[nt], aR[mt][nt], 0, 0, 0);
            }
    }
    #pragma unroll
    for (int mt = 0; mt < 4; ++mt)
        #pragma unroll
        for (int nt = 0; nt < 4; ++nt) {
            int d = (nt0 + nt) * 16 + n16;
            #pragma unroll
            for (int r = 0; r < 4; ++r) {
                int krow = mt * 16 + quad * 4 + r;
                size_t o = (((size_t)y * B_ + b) * K_ + krow) * D_ + d;
                PG[o] = aG[mt][nt][r];
                PR[o] = aR[mt][nt][r];
            }
        }
}

// ---------------------------------------------------------------------------
// Reduce partials: Gt = sum PtG, Gi = sum PiG, Racc = sum PtR + sum PiR
// ---------------------------------------------------------------------------
__global__ __launch_bounds__(256) void reduce_parts_kernel(
    const float* __restrict__ PtG, const float* __restrict__ PtR,
    const float* __restrict__ PiG, const float* __restrict__ PiR,
    float* __restrict__ Gt, float* __restrict__ Gi, float* __restrict__ Racc)
{
    const int BKD = B_ * K_ * D_;
    int idx = blockIdx.x * 256 + threadIdx.x;
    if (idx >= BKD) return;
    float gt = 0.f, gi = 0.f, r = 0.f;
    #pragma unroll
    for (int c = 0; c < 8; ++c) { gt += PtG[(size_t)c * BKD + idx]; r += PtR[(size_t)c * BKD + idx]; }
    #pragma unroll
    for (int c = 0; c < 8; ++c) { gi += PiG[(size_t)c * BKD + idx]; r += PiR[(size_t)c * BKD + idx]; }
    Gt[idx] = gt; Gi[idx] = gi; Racc[idx] = r;
}

// ---------------------------------------------------------------------------
// Final LN
// ---------------------------------------------------------------------------
__global__ __launch_bounds__(256) void final_ln_kernel(
    const float* __restrict__ stateTmp, const float* __restrict__ Racc,
    const float* __restrict__ rs_t, const float* __restrict__ rs_i,
    const float* __restrict__ b_tspf, const float* __restrict__ b_ispf,
    const float* __restrict__ state_init, const float* __restrict__ value_init,
    const float* __restrict__ stn_g, const float* __restrict__ stn_b,
    const float* __restrict__ vn_g, const float* __restrict__ vn_b,
    float* __restrict__ outState, float* __restrict__ outValue)
{
    __shared__ float pre[D_];
    __shared__ float red[256];
    int idx = blockIdx.x;
    int row = idx & 127;
    int isVal = idx >> 7;
    int tid = threadIdx.x;
    if (!isVal) {
        float rt = rs_t[row], ri = rs_i[row];
        for (int d = tid; d < D_; d += 256)
            pre[d] = stateTmp[(size_t)row * D_ + d] + rt * b_tspf[d] + ri * b_ispf[d]
                   + state_init[(size_t)row * D_ + d];
    } else {
        for (int d = tid; d < D_; d += 256)
            pre[d] = Racc[(size_t)row * D_ + d] + value_init[(size_t)row * D_ + d];
    }
    __syncthreads();
    float s = 0.f;
    for (int d = tid; d < D_; d += 256) s += pre[d];
    red[tid] = s; __syncthreads();
    for (int off = 128; off > 0; off >>= 1) { if (tid < off) red[tid] += red[tid + off]; __syncthreads(); }
    float mu = red[0] / (float)D_;
    __syncthreads();
    float v = 0.f;
    for (int d = tid; d < D_; d += 256) { float t = pre[d] - mu; v += t * t; }
    red[tid] = v; __syncthreads();
    for (int off = 128; off > 0; off >>= 1) { if (tid < off) red[tid] += red[tid + off]; __syncthreads(); }
    float rstd = rsqrtf(red[0] / (float)D_ + EPS_LN);
    const float* g  = isVal ? vn_g : stn_g;
    const float* bb = isVal ? vn_b : stn_b;
    float* o = (isVal ? outValue : outState) + (size_t)row * D_;
    for (int d = tid; d < D_; d += 256) o[d] = (pre[d] - mu) * rstd * g[d] + bb[d];
}

// ---------------------------------------------------------------------------
extern "C" void kernel_launch(void* const* d_in, const int* in_sizes, int n_in,
                              void* d_out, int out_size, void* d_ws, size_t ws_size,
                              hipStream_t stream) {
    const float* text_values  = (const float*)d_in[0];
    const float* image_values = (const float*)d_in[1];
    const float* lstate_init  = (const float*)d_in[2];
    const float* lvalue_init  = (const float*)d_in[3];
    const float* text_mask    = (const float*)d_in[4];
    const float* image_mask   = (const float*)d_in[5];
    const float* t_sn_g = (const float*)d_in[6];
    const float* t_sn_b = (const float*)d_in[7];
    const float* t_tn_g = (const float*)d_in[8];
    const float* t_tn_b = (const float*)d_in[9];
    const float* t_su_w = (const float*)d_in[10];
    const float* t_su_b = (const float*)d_in[11];
    const float* t_tp_w = (const float*)d_in[12];
    const float* t_tp_b = (const float*)d_in[13];
    const float* t_m1_w = (const float*)d_in[14];
    const float* t_m1_b = (const float*)d_in[15];
    const float* t_m2_w = (const float*)d_in[16];
    const float* t_m2_b = (const float*)d_in[17];
    const float* i_sn_g = (const float*)d_in[18];
    const float* i_sn_b = (const float*)d_in[19];
    const float* i_tn_g = (const float*)d_in[20];
    const float* i_tn_b = (const float*)d_in[21];
    const float* i_su_w = (const float*)d_in[22];
    const float* i_su_b = (const float*)d_in[23];
    const float* i_tp_w = (const float*)d_in[24];
    const float* i_tp_b = (const float*)d_in[25];
    const float* i_m1_w = (const float*)d_in[26];
    const float* i_m1_b = (const float*)d_in[27];
    const float* i_m2_w = (const float*)d_in[28];
    const float* i_m2_b = (const float*)d_in[29];
    const float* tsn_g = (const float*)d_in[30];
    const float* tsn_b = (const float*)d_in[31];
    const float* isn_g = (const float*)d_in[32];
    const float* isn_b = (const float*)d_in[33];
    const float* stn_g = (const float*)d_in[34];
    const float* stn_b = (const float*)d_in[35];
    const float* vn_g  = (const float*)d_in[36];
    const float* vn_b  = (const float*)d_in[37];
    const float* tsp_w = (const float*)d_in[38];
    const float* tsp_b = (const float*)d_in[39];
    const float* isp_w = (const float*)d_in[40];
    const float* isp_b = (const float*)d_in[41];

    float* ws = (float*)d_ws;
    size_t o = 0;
    float* xhat_text  = ws + o; o += (size_t)B_ * ST_ * D_;
    float* xhat_image = ws + o; o += (size_t)B_ * SI_ * D_;
    float* xhat_lat   = ws + o; o += (size_t)B_ * K_  * D_;
    float* b_su_t = ws + o; o += E_;
    float* b_su_i = ws + o; o += E_;
    float* b_tp_t = ws + o; o += E_;
    float* b_tp_i = ws + o; o += E_;
    float* b_tspf = ws + o; o += D_;
    float* b_ispf = ws + o; o += D_;
    float* t_t  = ws + o; o += (size_t)B_ * K_ * E_;
    float* t_i  = ws + o; o += (size_t)B_ * K_ * E_;
    float* c2_t = ws + o; o += (size_t)B_ * K_ * E_;
    float* c2_i = ws + o; o += (size_t)B_ * K_ * E_;
    // bf16 buffers (element counts halved into float units, keep 16B align)
    ushort_t* AF_text = (ushort_t*)(ws + o); o += (size_t)B_ * ST_ * D_ / 2;
    ushort_t* AF_img  = (ushort_t*)(ws + o); o += (size_t)B_ * SI_ * D_ / 2;
    ushort_t* WsuF_t  = (ushort_t*)(ws + o); o += (size_t)D_ * E_ / 2;
    ushort_t* WsuF_i  = (ushort_t*)(ws + o); o += (size_t)D_ * E_ / 2;
    ushort_t* sF_text = (ushort_t*)(ws + o); o += (size_t)B_ * ST_ * E_ / 2;
    ushort_t* sF_img  = (ushort_t*)(ws + o); o += (size_t)B_ * SI_ * E_ / 2;
    ushort_t* MF_t = (ushort_t*)(ws + o); o += (size_t)B_ * K_ * E_ * E_ / 2;
    ushort_t* MF_i = (ushort_t*)(ws + o); o += (size_t)B_ * K_ * E_ * E_ / 2;
    ushort_t* XhF_t = (ushort_t*)(ws + o); o += (size_t)B_ * ST_ * D_ / 2;
    ushort_t* XhF_i = (ushort_t*)(ws + o); o += (size_t)B_ * SI_ * D_ / 2;
    ushort_t* XrF_t = (ushort_t*)(ws + o); o += (size_t)B_ * ST_ * D_ / 2;
    ushort_t* XrF_i = (ushort_t*)(ws + o); o += (size_t)B_ * SI_ * D_ / 2;
    ushort_t* EF_t  = (ushort_t*)(ws + o); o += (size_t)B_ * ST_ * K_ / 2;
    ushort_t* EF_i  = (ushort_t*)(ws + o); o += (size_t)B_ * SI_ * K_ / 2;
    const int BKD = B_ * K_ * D_;
    float* PtG = ws + o; o += (size_t)8 * BKD;
    float* PtR = ws + o; o += (size_t)8 * BKD;
    float* PiG = ws + o; o += (size_t)8 * BKD;
    float* PiR = ws + o; o += (size_t)8 * BKD;
    float* Gt   = ws + o; o += BKD;
    float* Gi   = ws + o; o += BKD;
    float* Racc = ws + o; o += BKD;
    float* rs_t = ws + o; o += B_ * K_;
    float* rs_i = ws + o; o += B_ * K_;
    float* state_tmp = ws + o; o += BKD;

    float* outState = (float*)d_out;                       // [B,K,D]
    float* outValue = (float*)d_out + (size_t)B_ * K_ * D_;
    float* t2l = (float*)d_out + 2 * (size_t)B_ * K_ * D_;             // [B,ST,K]
    float* i2l = t2l + (size_t)B_ * ST_ * K_;                          // [B,SI,K]

    // --- bias folds ---
    fold_b_kernel<<<E_ / 64, 256, 0, stream>>>(t_sn_b, t_su_w, t_su_b, b_su_t, D_, E_);
    fold_b_kernel<<<E_ / 64, 256, 0, stream>>>(i_sn_b, i_su_w, i_su_b, b_su_i, D_, E_);
    fold_b_kernel<<<E_ / 64, 256, 0, stream>>>(t_tn_b, t_tp_w, t_tp_b, b_tp_t, D_, E_);
    fold_b_kernel<<<E_ / 64, 256, 0, stream>>>(i_tn_b, i_tp_w, i_tp_b, b_tp_i, D_, E_);
    fold_b_kernel<<<D_ / 64, 256, 0, stream>>>(tsn_b, tsp_w, tsp_b, b_tspf, D_, D_);
    fold_b_kernel<<<D_ / 64, 256, 0, stream>>>(isn_b, isp_w, isp_b, b_ispf, D_, D_);

    // --- xhat ---
    ln_xhat_kernel<<<B_ * ST_, 256, 0, stream>>>(text_values, xhat_text);
    ln_xhat_kernel<<<B_ * SI_, 256, 0, stream>>>(image_values, xhat_image);
    ln_xhat_kernel<<<B_ * K_,  256, 0, stream>>>(lvalue_init, xhat_lat);

    // --- packs for s-proj GEMM ---
    packA_kernel<<<((B_ * ST_ / 16) * 24 * 64 + 255) / 256, 256, 0, stream>>>(xhat_text, AF_text, B_ * ST_, D_);
    packA_kernel<<<((B_ * SI_ / 16) * 24 * 64 + 255) / 256, 256, 0, stream>>>(xhat_image, AF_img, B_ * SI_, D_);
    packB_kernel<<<((D_ / 32) * (E_ / 16) * 64 + 255) / 256, 256, 0, stream>>>(t_su_w, t_sn_g, WsuF_t, D_, E_);
    packB_kernel<<<((D_ / 32) * (E_ / 16) * 64 + 255) / 256, 256, 0, stream>>>(i_su_w, i_sn_g, WsuF_i, D_, E_);
    // --- packs for einsum (B operands) ---
    packB_kernel<<<((B_ * ST_ / 32) * (D_ / 16) * 64 + 255) / 256, 256, 0, stream>>>(xhat_text, nullptr, XhF_t, B_ * ST_, D_);
    packB_kernel<<<((B_ * SI_ / 32) * (D_ / 16) * 64 + 255) / 256, 256, 0, stream>>>(xhat_image, nullptr, XhF_i, B_ * SI_, D_);
    packB_kernel<<<((B_ * ST_ / 32) * (D_ / 16) * 64 + 255) / 256, 256, 0, stream>>>(text_values, nullptr, XrF_t, B_ * ST_, D_);
    packB_kernel<<<((B_ * SI_ / 32) * (D_ / 16) * 64 + 255) / 256, 256, 0, stream>>>(image_values, nullptr, XrF_i, B_ * SI_, D_);

    dim3 blk16(16, 16);
    // t projections (fp32, tiny): [128,768]@[768,256], rowScale = tn_g
    sgemm_kernel<<<dim3(E_ / 64, B_ * K_ / 64), blk16, 0, stream>>>(xhat_lat, t_tp_w, t_tn_g, b_tp_t, t_t, B_ * K_, E_, D_, 0);
    sgemm_kernel<<<dim3(E_ / 64, B_ * K_ / 64), blk16, 0, stream>>>(xhat_lat, i_tp_w, i_tn_g, b_tp_i, t_i, B_ * K_, E_, D_, 0);
    // c2 = t @ W2 + m1_b
    sgemm_kernel<<<dim3(E_ / 64, B_ * K_ / 64), blk16, 0, stream>>>(t_t, t_m1_w + (size_t)E_ * E_, nullptr, t_m1_b, c2_t, B_ * K_, E_, E_, 0);
    sgemm_kernel<<<dim3(E_ / 64, B_ * K_ / 64), blk16, 0, stream>>>(t_i, i_m1_w + (size_t)E_ * E_, nullptr, i_m1_b, c2_i, B_ * K_, E_, E_, 0);

    // --- s projections via MFMA, fused pack into sF ---
    sproj_mfma_kernel<<<B_ * ST_ / 64, 256, 0, stream>>>(AF_text, WsuF_t, b_su_t, sF_text, B_ * ST_);
    sproj_mfma_kernel<<<B_ * SI_ / 64, 256, 0, stream>>>(AF_img, WsuF_i, b_su_i, sF_img, B_ * SI_);

    // --- pack M ---
    pack_M_kernel<<<(B_ * K_ * 16 * 8 * 64) / 256, 256, 0, stream>>>(t_t, t_m1_w + 2 * (size_t)E_ * E_, t_m1_w, MF_t);
    pack_M_kernel<<<(B_ * K_ * 16 * 8 * 64) / 256, 256, 0, stream>>>(t_i, i_m1_w + 2 * (size_t)E_ * E_, i_m1_w, MF_i);

    // --- cross + edge ---
    cross_mfma_kernel<<<dim3(ST_ / 128, K_, B_), 256, 0, stream>>>(
        sF_text, MF_t, c2_t, t_m2_w, t_m2_b, text_mask, t2l, EF_t, ST_);
    cross_mfma_kernel<<<dim3(SI_ / 128, K_, B_), 256, 0, stream>>>(
        sF_img, MF_i, c2_i, i_m2_w, i_m2_b, image_mask, i2l, EF_i, SI_);

    // --- aggregation ---
    rowsum_kernel<<<B_ * K_, 256, 0, stream>>>(t2l, rs_t, ST_);
    rowsum_kernel<<<B_ * K_, 256, 0, stream>>>(i2l, rs_i, SI_);
    einsum_mfma_kernel<<<dim3(3, 8, B_), 256, 0, stream>>>(EF_t, XhF_t, XrF_t, PtG, PtR, ST_, ST_ / 256);
    einsum_mfma_kernel<<<dim3(3, 8, B_), 256, 0, stream>>>(EF_i, XhF_i, XrF_i, PiG, PiR, SI_, SI_ / 256);
    reduce_parts_kernel<<<(BKD + 255) / 256, 256, 0, stream>>>(PtG, PtR, PiG, PiR, Gt, Gi, Racc);

    // state_tmp = Gt@(tsn_g*tsp_w) + Gi@(isn_g*isp_w)
    sgemm_kernel<<<dim3(D_ / 64, B_ * K_ / 64), blk16, 0, stream>>>(Gt, tsp_w, tsn_g, nullptr, state_tmp, B_ * K_, D_, D_, 0);
    sgemm_kernel<<<dim3(D_ / 64, B_ * K_ / 64), blk16, 0, stream>>>(Gi, isp_w, isn_g, nullptr, state_tmp, B_ * K_, D_, D_, 1);

    // --- final LN ---
    final_ln_kernel<<<2 * B_ * K_, 256, 0, stream>>>(
        state_tmp, Racc, rs_t, rs_i, b_tspf, b_ispf,
        lstate_init, lvalue_init, stn_g, stn_b, vn_g, vn_b, outState, outValue);
}

// Round 4
// 372.892 us; speedup vs baseline: 8.0356x; 2.8499x over previous
//
#include <hip/hip_runtime.h>
#include <math.h>

#define EPS_LN 1e-5f

#define B_  2
#define ST_ 2048
#define SI_ 1024
#define K_  64
#define D_  768
#define E_  256

typedef __bf16 bf16x8 __attribute__((ext_vector_type(8)));
typedef float  f32x4  __attribute__((ext_vector_type(4)));
typedef unsigned short ushort_t;

__device__ inline ushort_t f2bf(float x) {
    unsigned int u = __float_as_uint(x);
    unsigned int r = (u + 0x7FFFu + ((u >> 16) & 1u)) >> 16;
    return (ushort_t)r;
}

// A&S 7.1.26 erf approximation, |err| <= 1.5e-7
__device__ inline float erf_fast(float x) {
    float ax = fabsf(x);
    float t = __builtin_amdgcn_rcpf(fmaf(0.3275911f, ax, 1.0f));
    float poly = t * (0.254829592f + t * (-0.284496736f + t * (1.421413741f +
                 t * (-1.453152027f + t * 1.061405429f))));
    float y = 1.0f - poly * __expf(-ax * ax);
    return copysignf(y, x);
}
__device__ inline float gelu_fast(float z) {
    return 0.5f * z * (1.0f + erf_fast(z * 0.70710678118654752f));
}

// ---------------------------------------------------------------------------
// ln_stats: one wave per row over {text(4096), image(2048), latent(128)} rows.
// ---------------------------------------------------------------------------
__global__ __launch_bounds__(256) void ln_stats_kernel(
    const float* __restrict__ xt, const float* __restrict__ xi,
    const float* __restrict__ xl, float* __restrict__ mu, float* __restrict__ rstd)
{
    int w = threadIdx.x >> 6, lane = threadIdx.x & 63;
    int row = blockIdx.x * 4 + w;
    const float* src;
    if (row < 4096) src = xt + (size_t)row * D_;
    else if (row < 6144) src = xi + (size_t)(row - 4096) * D_;
    else src = xl + (size_t)(row - 6144) * D_;
    float s = 0.f, q = 0.f;
    #pragma unroll
    for (int rep = 0; rep < 3; ++rep) {
        float4 v = *(const float4*)(src + lane * 4 + rep * 256);
        s += v.x + v.y + v.z + v.w;
        q += v.x * v.x + v.y * v.y + v.z * v.z + v.w * v.w;
    }
    #pragma unroll
    for (int off = 32; off > 0; off >>= 1) {
        s += __shfl_xor(s, off, 64);
        q += __shfl_xor(q, off, 64);
    }
    if (lane == 0) {
        float m = s / (float)D_;
        float var = q / (float)D_ - m * m;
        mu[row] = m;
        rstd[row] = rsqrtf(var + EPS_LN);
    }
}

// ---------------------------------------------------------------------------
// fold_all: bf[e] += sum_d bln[d]*W[d,e] (+wb[e] once). 6 configs via bz.
// grid (12, 12, 6), block 256.
// ---------------------------------------------------------------------------
__global__ __launch_bounds__(256) void fold_all_kernel(
    const float* b0, const float* W0, const float* w0, float* f0,
    const float* b1, const float* W1, const float* w1, float* f1,
    const float* b2, const float* W2, const float* w2, float* f2,
    const float* b3, const float* W3, const float* w3, float* f3,
    const float* b4, const float* W4, const float* w4, float* f4,
    const float* b5, const float* W5, const float* w5, float* f5)
{
    const float* blns[6] = {b0, b1, b2, b3, b4, b5};
    const float* Ws[6]   = {W0, W1, W2, W3, W4, W5};
    const float* wbs[6]  = {w0, w1, w2, w3, w4, w5};
    float* bfs[6]        = {f0, f1, f2, f3, f4, f5};
    int cfg = blockIdx.z;
    int E = (cfg >= 4) ? 768 : 256;
    if ((int)blockIdx.x * 64 >= E) return;
    const float* bln = blns[cfg];
    const float* W = Ws[cfg];
    __shared__ float red[4][64];
    int c = threadIdx.x & 63, part = threadIdx.x >> 6;
    int e = blockIdx.x * 64 + c;
    int d0 = blockIdx.y * 64;
    float s = 0.f;
    #pragma unroll
    for (int i = 0; i < 16; ++i) {
        int d = d0 + part * 16 + i;
        s += bln[d] * W[(size_t)d * E + e];
    }
    red[part][c] = s; __syncthreads();
    if (part == 0) {
        float v = red[0][c] + red[1][c] + red[2][c] + red[3][c];
        if (blockIdx.y == 0 && wbs[cfg]) v += wbs[cfg][e];
        atomicAdd(&bfs[cfg][e], v);
    }
}

// ---------------------------------------------------------------------------
// transpose_pack: one coalesced pass over x -> XrF (raw, B-frag), XhF (xhat,
// B-frag), AF (xhat, A-frag). grid (96, 12): bx<64 text, else image.
// ---------------------------------------------------------------------------
__global__ __launch_bounds__(256) void tpack_kernel(
    const float* __restrict__ xt, const float* __restrict__ xi,
    const float* __restrict__ mu, const float* __restrict__ rstd,
    ushort_t* __restrict__ XrF_t, ushort_t* __restrict__ XhF_t, ushort_t* __restrict__ AF_t,
    ushort_t* __restrict__ XrF_i, ushort_t* __restrict__ XhF_i, ushort_t* __restrict__ AF_i)
{
    __shared__ float tile[64][65];
    __shared__ float mu_s[64], rs_s[64];
    int bx = blockIdx.x;
    int isImg = bx >= 64;
    const float* x = isImg ? xi : xt;
    ushort_t* XrF = isImg ? XrF_i : XrF_t;
    ushort_t* XhF = isImg ? XhF_i : XhF_t;
    ushort_t* AF  = isImg ? AF_i  : AF_t;
    int rbase = (isImg ? bx - 64 : bx) * 64;
    int statOff = isImg ? 4096 : 0;
    int d0 = blockIdx.y * 64;
    int t = threadIdx.x;
    #pragma unroll
    for (int rep = 0; rep < 4; ++rep) {
        int rl = (t >> 4) + rep * 16;
        int c4 = (t & 15) * 4;
        *(float4*)&tile[rl][c4] = *(const float4*)(x + (size_t)(rbase + rl) * D_ + d0 + c4);
    }
    if (t < 64) { mu_s[t] = mu[statOff + rbase + t]; rs_s[t] = rstd[statOff + rbase + t]; }
    __syncthreads();
    int lane = t & 63;
    // XrF / XhF (B-frag): 512 uint4 each
    #pragma unroll
    for (int rep = 0; rep < 2; ++rep) {
        int idx = t + rep * 256;
        int nt = (idx >> 6) & 3, cl = (idx >> 8) & 1;
        int kl = cl * 32 + (lane >> 4) * 8;
        int nl = nt * 16 + (lane & 15);
        ushort_t orw[8], oh[8];
        #pragma unroll
        for (int j = 0; j < 8; ++j) {
            float v = tile[kl + j][nl];
            orw[j] = f2bf(v);
            oh[j]  = f2bf((v - mu_s[kl + j]) * rs_s[kl + j]);
        }
        size_t chunk = (size_t)((rbase >> 5) + cl);
        size_t o = ((chunk * 48 + (d0 >> 4) + nt) * 64 + lane) * 8;
        *reinterpret_cast<uint4*>(XrF + o) = *reinterpret_cast<uint4*>(orw);
        *reinterpret_cast<uint4*>(XhF + o) = *reinterpret_cast<uint4*>(oh);
    }
    // AF (A-frag): 512 uint4
    #pragma unroll
    for (int rep = 0; rep < 2; ++rep) {
        int idx = t + rep * 256;
        int cl = (idx >> 6) & 1, tl = idx >> 7;
        int rl = tl * 16 + (lane & 15);
        int dl = cl * 32 + (lane >> 4) * 8;
        float m = mu_s[rl], rs = rs_s[rl];
        ushort_t o8[8];
        #pragma unroll
        for (int j = 0; j < 8; ++j)
            o8[j] = f2bf((tile[rl][dl + j] - m) * rs);
        size_t o = (((size_t)(rbase >> 4) + tl) * 24 + (d0 >> 5) + cl) * 512 + lane * 8;
        *reinterpret_cast<uint4*>(AF + o) = *reinterpret_cast<uint4*>(o8);
    }
}

// ---------------------------------------------------------------------------
// packB: fp32 [Kd][N] (optional row scale) -> bf16 B-frags (for weight packs)
// ---------------------------------------------------------------------------
__global__ __launch_bounds__(256) void packB_kernel(const float* __restrict__ W,
                                                    const float* __restrict__ g,
                                                    ushort_t* __restrict__ out,
                                                    int Kd, int N) {
    int idx = blockIdx.x * 256 + threadIdx.x;
    int nTile = N >> 4;
    int total = (Kd >> 5) * nTile * 64;
    if (idx >= total) return;
    int lane = idx & 63;
    int ntile = (idx >> 6) % nTile;
    int c = idx / (64 * nTile);
    int n = ntile * 16 + (lane & 15);
    int k0 = c * 32 + (lane >> 4) * 8;
    ushort_t o[8];
    #pragma unroll
    for (int j = 0; j < 8; ++j) {
        int k = k0 + j;
        float v = W[(size_t)k * N + n];
        if (g) v *= g[k];
        o[j] = f2bf(v);
    }
    *reinterpret_cast<uint4*>(out + (size_t)idx * 8) = *reinterpret_cast<uint4*>(o);
}

// ---------------------------------------------------------------------------
// sgemm_split: C[M=128,N] += A[128,Kd]@B (optional A-LN, B rowScale, bias at
// kz==0) via split-K atomics. grid (N/64, 2, nz0+nz1), block (16,16).
// ---------------------------------------------------------------------------
__global__ __launch_bounds__(256) void sgemm_split_kernel(
    const float* A0, const float* B0, const float* rs0, const float* bias0,
    const float* mu0, const float* sd0, int so0, float* C0,
    const float* A1, const float* B1, const float* rs1, const float* bias1,
    const float* mu1, const float* sd1, int so1, float* C1,
    int nz0, int Kd, int N)
{
    int z = blockIdx.z;
    int cfg = (z >= nz0) ? 1 : 0;
    int kz = cfg ? (z - nz0) : z;
    const float* A = cfg ? A1 : A0;
    const float* Bm = cfg ? B1 : B0;
    const float* rowScale = cfg ? rs1 : rs0;
    const float* bias = cfg ? bias1 : bias0;
    const float* muA = cfg ? mu1 : mu0;
    const float* sdA = cfg ? sd1 : sd0;
    int so = cfg ? so1 : so0;
    float* C = cfg ? C1 : C0;

    __shared__ float As[16][65];
    __shared__ float Bs[16][64];
    int tx = threadIdx.x, ty = threadIdx.y;
    int tid = ty * 16 + tx;
    int row0 = blockIdx.y * 64;
    int col0 = blockIdx.x * 64;
    float acc[4][4] = {};
    int kbase = kz * 128;
    for (int k0 = kbase; k0 < kbase + 128; k0 += 16) {
        {
            int e = tid * 4;
            int r = e >> 4, kk = e & 15;
            float4 av = *(const float4*)(A + (size_t)(row0 + r) * Kd + k0 + kk);
            if (muA) {
                float m = muA[so + row0 + r], sd = sdA[so + row0 + r];
                av.x = (av.x - m) * sd; av.y = (av.y - m) * sd;
                av.z = (av.z - m) * sd; av.w = (av.w - m) * sd;
            }
            As[kk + 0][r] = av.x; As[kk + 1][r] = av.y; As[kk + 2][r] = av.z; As[kk + 3][r] = av.w;
        }
        {
            int e = tid * 4;
            int kk = e >> 6, c = e & 63;
            float4 bv = *(const float4*)(Bm + (size_t)(k0 + kk) * N + col0 + c);
            if (rowScale) {
                float sc = rowScale[k0 + kk];
                bv.x *= sc; bv.y *= sc; bv.z *= sc; bv.w *= sc;
            }
            *(float4*)&Bs[kk][c] = bv;
        }
        __syncthreads();
        #pragma unroll
        for (int kk = 0; kk < 16; ++kk) {
            float a[4], b[4];
            #pragma unroll
            for (int i = 0; i < 4; ++i) a[i] = As[kk][ty + 16 * i];
            #pragma unroll
            for (int j = 0; j < 4; ++j) b[j] = Bs[kk][tx + 16 * j];
            #pragma unroll
            for (int i = 0; i < 4; ++i)
                #pragma unroll
                for (int j = 0; j < 4; ++j)
                    acc[i][j] += a[i] * b[j];
        }
        __syncthreads();
    }
    #pragma unroll
    for (int i = 0; i < 4; ++i) {
        int r = row0 + ty + 16 * i;
        #pragma unroll
        for (int j = 0; j < 4; ++j) {
            int c = col0 + tx + 16 * j;
            float v = acc[i][j];
            if (kz == 0 && bias) v += bias[c];
            atomicAdd(&C[(size_t)r * N + c], v);
        }
    }
}

// ---------------------------------------------------------------------------
// sproj: s = xhat@Wf + bias directly into sF A-frags. grid 192: bx<128 text.
// Wave w: 32 rows x cols [64w,64w+64).
// ---------------------------------------------------------------------------
__global__ __launch_bounds__(256) void sproj_mfma_kernel(
    const ushort_t* __restrict__ AF_t, const ushort_t* __restrict__ BF_t,
    const float* __restrict__ bias_t, ushort_t* __restrict__ sF_t,
    const ushort_t* __restrict__ AF_i, const ushort_t* __restrict__ BF_i,
    const float* __restrict__ bias_i, ushort_t* __restrict__ sF_i)
{
    __shared__ __align__(16) ushort_t ls[4][32][72];
    int bx = blockIdx.x;
    int isImg = bx >= 128;
    const ushort_t* AF = isImg ? AF_i : AF_t;
    const ushort_t* BF = isImg ? BF_i : BF_t;
    const float* bias = isImg ? bias_i : bias_t;
    ushort_t* sF = isImg ? sF_i : sF_t;
    int tile0 = (isImg ? bx - 128 : bx) * 2;

    int w = threadIdx.x >> 6, lane = threadIdx.x & 63;
    int quad = lane >> 4, n16 = lane & 15;

    f32x4 acc[2][4];
    #pragma unroll
    for (int mt = 0; mt < 2; ++mt)
        #pragma unroll
        for (int nt = 0; nt < 4; ++nt)
            acc[mt][nt] = (f32x4){0.f, 0.f, 0.f, 0.f};

    for (int c = 0; c < 24; ++c) {
        bf16x8 af[2], bf[4];
        #pragma unroll
        for (int mt = 0; mt < 2; ++mt)
            af[mt] = *reinterpret_cast<const bf16x8*>(AF + ((size_t)(tile0 + mt) * 24 + c) * 512 + lane * 8);
        #pragma unroll
        for (int nt = 0; nt < 4; ++nt)
            bf[nt] = *reinterpret_cast<const bf16x8*>(BF + ((size_t)c * 16 + w * 4 + nt) * 512 + lane * 8);
        #pragma unroll
        for (int mt = 0; mt < 2; ++mt)
            #pragma unroll
            for (int nt = 0; nt < 4; ++nt)
                acc[mt][nt] = __builtin_amdgcn_mfma_f32_16x16x32_bf16(af[mt], bf[nt], acc[mt][nt], 0, 0, 0);
    }
    #pragma unroll
    for (int mt = 0; mt < 2; ++mt)
        #pragma unroll
        for (int nt = 0; nt < 4; ++nt) {
            float bv = bias[w * 64 + nt * 16 + n16];
            #pragma unroll
            for (int r = 0; r < 4; ++r)
                ls[w][mt * 16 + quad * 4 + r][nt * 16 + n16] = f2bf(acc[mt][nt][r] + bv);
        }
    __syncthreads();
    #pragma unroll
    for (int mt = 0; mt < 2; ++mt)
        #pragma unroll
        for (int h = 0; h < 2; ++h) {
            uint4 v = *reinterpret_cast<const uint4*>(&ls[w][mt * 16 + n16][h * 32 + quad * 8]);
            *reinterpret_cast<uint4*>(sF + ((size_t)(tile0 + mt) * 8 + 2 * w + h) * 512 + lane * 8) = v;
        }
}

// ---------------------------------------------------------------------------
// pack M_k = t[k,e]*W3[e,j] + W1[e,j] -> bf16 B-frags. Combined text+image.
// ---------------------------------------------------------------------------
__global__ __launch_bounds__(256) void pack_M_kernel(
    const float* __restrict__ tP_t, const float* __restrict__ W3_t,
    const float* __restrict__ W1_t, ushort_t* __restrict__ MF_t,
    const float* __restrict__ tP_i, const float* __restrict__ W3_i,
    const float* __restrict__ W1_i, ushort_t* __restrict__ MF_i)
{
    const int HALF = B_ * K_ * 16 * 8 * 64;
    int gidx = blockIdx.x * 256 + threadIdx.x;
    int isImg = gidx >= HALF;
    int idx = isImg ? gidx - HALF : gidx;
    const float* tP = isImg ? tP_i : tP_t;
    const float* W3 = isImg ? W3_i : W3_t;
    const float* W1 = isImg ? W1_i : W1_t;
    ushort_t* MF = isImg ? MF_i : MF_t;
    int lane = idx & 63;
    int kc = (idx >> 6) & 7;
    int nt = (idx >> 9) & 15;
    int bk = idx >> 13;
    int n = nt * 16 + (lane & 15);
    int e0 = kc * 32 + (lane >> 4) * 8;
    ushort_t out[8];
    #pragma unroll
    for (int j = 0; j < 8; ++j) {
        int e = e0 + j;
        float v = tP[(size_t)bk * E_ + e] * W3[(size_t)e * E_ + n] + W1[(size_t)e * E_ + n];
        out[j] = f2bf(v);
    }
    *reinterpret_cast<uint4*>(MF + (size_t)idx * 8) = *reinterpret_cast<uint4*>(out);
}

// ---------------------------------------------------------------------------
// Cross + edge via MFMA, combined text+image. grid (48, 64, 2), block 256.
// bx<32: text s-tile, else image. Wave w: 64 rows x cols [64w,64w+64).
// Fused rowsum atomic.
// ---------------------------------------------------------------------------
__global__ __launch_bounds__(256, 4) void cross_mfma_kernel(
    const ushort_t* __restrict__ sF_t, const ushort_t* __restrict__ MF_t,
    const float* __restrict__ c2_t, const float* __restrict__ m2w_t,
    const float* __restrict__ m2b_t, const float* __restrict__ mask_t,
    float* __restrict__ out_t, ushort_t* __restrict__ EFt, float* __restrict__ rsum_t,
    const ushort_t* __restrict__ sF_i, const ushort_t* __restrict__ MF_i,
    const float* __restrict__ c2_i, const float* __restrict__ m2w_i,
    const float* __restrict__ m2b_i, const float* __restrict__ mask_i,
    float* __restrict__ out_i, ushort_t* __restrict__ EFi, float* __restrict__ rsum_i)
{
    int bx = blockIdx.x;
    int isImg = bx >= 32;
    int S = isImg ? SI_ : ST_;
    const ushort_t* sF = isImg ? sF_i : sF_t;
    const ushort_t* MF = isImg ? MF_i : MF_t;
    const float* c2P = isImg ? c2_i : c2_t;
    const float* m2w = isImg ? m2w_i : m2w_t;
    const float* m2b = isImg ? m2b_i : m2b_t;
    const float* mask = isImg ? mask_i : mask_t;
    float* outE = isImg ? out_i : out_t;
    ushort_t* EF = isImg ? EFi : EFt;
    float* rsum = isImg ? rsum_i : rsum_t;
    int s0 = (isImg ? bx - 32 : bx) * 64;
    int k = blockIdx.y;
    int b = blockIdx.z;
    int tid = threadIdx.x;
    int w = tid >> 6, lane = tid & 63;
    int quad = lane >> 4, n16 = lane & 15;

    const ushort_t* aBase = sF + (size_t)(b * (S / 16) + (s0 >> 4)) * 4096;
    const ushort_t* bBase = MF + ((size_t)(b * K_ + k) * 16 + w * 4) * 4096;

    f32x4 acc[4][4];
    #pragma unroll
    for (int mt = 0; mt < 4; ++mt)
        #pragma unroll
        for (int nt = 0; nt < 4; ++nt)
            acc[mt][nt] = (f32x4){0.f, 0.f, 0.f, 0.f};

    #pragma unroll
    for (int kc = 0; kc < 8; ++kc) {
        bf16x8 bfr[4], af[4];
        #pragma unroll
        for (int nt = 0; nt < 4; ++nt)
            bfr[nt] = *reinterpret_cast<const bf16x8*>(bBase + (size_t)nt * 4096 + kc * 512 + lane * 8);
        #pragma unroll
        for (int mt = 0; mt < 4; ++mt)
            af[mt] = *reinterpret_cast<const bf16x8*>(aBase + (size_t)mt * 4096 + kc * 512 + lane * 8);
        #pragma unroll
        for (int mt = 0; mt < 4; ++mt)
            #pragma unroll
            for (int nt = 0; nt < 4; ++nt)
                acc[mt][nt] = __builtin_amdgcn_mfma_f32_16x16x32_bf16(af[mt], bfr[nt], acc[mt][nt], 0, 0, 0);
    }

    const float* c2v = c2P + (size_t)(b * K_ + k) * E_;
    float c2r[4], m2r[4];
    #pragma unroll
    for (int nt = 0; nt < 4; ++nt) {
        int col = w * 64 + nt * 16 + n16;
        c2r[nt] = c2v[col];
        m2r[nt] = m2w[col];
    }
    __shared__ float pPart[4][64];
    #pragma unroll
    for (int mt = 0; mt < 4; ++mt) {
        #pragma unroll
        for (int r = 0; r < 4; ++r) {
            float p = 0.f;
            #pragma unroll
            for (int nt = 0; nt < 4; ++nt) {
                float z = acc[mt][nt][r] + c2r[nt];
                p += gelu_fast(z) * m2r[nt];
            }
            p += __shfl_xor(p, 1, 64);
            p += __shfl_xor(p, 2, 64);
            p += __shfl_xor(p, 4, 64);
            p += __shfl_xor(p, 8, 64);
            if (n16 == 0) pPart[w][mt * 16 + quad * 4 + r] = p;
        }
    }
    __syncthreads();
    if (tid < 64) {
        float e = pPart[0][tid] + pPart[1][tid] + pPart[2][tid] + pPart[3][tid] + m2b[0];
        e = e / (1.0f + fabsf(e));
        int srow = s0 + tid;
        e *= mask[(size_t)b * S + srow];
        outE[((size_t)b * S + srow) * K_ + k] = e;
        int c = (b * S + srow) >> 5;
        int mt = k >> 4;
        int lp = (k & 15) + (((srow >> 3) & 3) << 4);
        EF[(((size_t)c * 4 + mt) * 64 + lp) * 8 + (srow & 7)] = f2bf(e);
        // fused rowsum
        float se = e;
        #pragma unroll
        for (int off = 32; off > 0; off >>= 1) se += __shfl_xor(se, off, 64);
        if (tid == 0) atomicAdd(&rsum[b * K_ + k], se);
    }
}

// ---------------------------------------------------------------------------
// einsum via MFMA, combined. grid (3, 8, 4): bz<2 text (b=bz), else image.
// ---------------------------------------------------------------------------
__global__ __launch_bounds__(256, 2) void einsum_mfma_kernel(
    const ushort_t* __restrict__ EF_t, const ushort_t* __restrict__ XhF_t,
    const ushort_t* __restrict__ XrF_t, float* __restrict__ PtG, float* __restrict__ PtR,
    const ushort_t* __restrict__ EF_i, const ushort_t* __restrict__ XhF_i,
    const ushort_t* __restrict__ XrF_i, float* __restrict__ PiG, float* __restrict__ PiR)
{
    int bz = blockIdx.z;
    int isImg = bz >= 2;
    int b = isImg ? bz - 2 : bz;
    int S = isImg ? SI_ : ST_;
    const ushort_t* EF = isImg ? EF_i : EF_t;
    const ushort_t* XhF = isImg ? XhF_i : XhF_t;
    const ushort_t* XrF = isImg ? XrF_i : XrF_t;
    float* PG = isImg ? PiG : PtG;
    float* PR = isImg ? PiR : PtR;
    int chunksPerBlock = S / 256;

    int w = threadIdx.x >> 6, lane = threadIdx.x & 63;
    int quad = lane >> 4, n16 = lane & 15;
    int y = blockIdx.y;
    int nt0 = blockIdx.x * 16 + w * 4;
    size_t cb = (size_t)(b * S) / 32 + (size_t)y * chunksPerBlock;

    f32x4 aG[4][4], aR[4][4];
    #pragma unroll
    for (int mt = 0; mt < 4; ++mt)
        #pragma unroll
        for (int nt = 0; nt < 4; ++nt) {
            aG[mt][nt] = (f32x4){0.f, 0.f, 0.f, 0.f};
            aR[mt][nt] = (f32x4){0.f, 0.f, 0.f, 0.f};
        }

    for (int cc = 0; cc < chunksPerBlock; ++cc) {
        size_t c = cb + cc;
        bf16x8 af[4], bh[4], bx[4];
        #pragma unroll
        for (int mt = 0; mt < 4; ++mt)
            af[mt] = *reinterpret_cast<const bf16x8*>(EF + ((c * 4 + mt) * 64 + lane) * 8);
        #pragma unroll
        for (int nt = 0; nt < 4; ++nt) {
            bh[nt] = *reinterpret_cast<const bf16x8*>(XhF + ((c * 48 + nt0 + nt) * 64 + lane) * 8);
            bx[nt] = *reinterpret_cast<const bf16x8*>(XrF + ((c * 48 + nt0 + nt) * 64 + lane) * 8);
        }
        #pragma unroll
        for (int mt = 0; mt < 4; ++mt)
            #pragma unroll
            for (int nt = 0; nt < 4; ++nt) {
                aG[mt][nt] = __builtin_amdgcn_mfma_f32_16x16x32_bf16(af[mt], bh[nt], aG[mt][nt], 0, 0, 0);
                aR[mt][nt] = __builtin_amdgcn_mfma_f32_16x16x32_bf16(af[mt], bx[nt], aR[mt][nt], 0, 0, 0);
            }
    }
    #pragma unroll
    for (int mt = 0; mt < 4; ++mt)
        #pragma unroll
        for (int nt = 0; nt < 4; ++nt) {
            int d = (nt0 + nt) * 16 + n16;
            #pragma unroll
            for (int r = 0; r < 4; ++r) {
                int krow = mt * 16 + quad * 4 + r;
                size_t o = (((size_t)y * B_ + b) * K_ + krow) * D_ + d;
                PG[o] = aG[mt][nt][r];
                PR[o] = aR[mt][nt][r];
            }
        }
}

// ---------------------------------------------------------------------------
__global__ __launch_bounds__(256) void reduce_parts_kernel(
    const float* __restrict__ PtG, const float* __restrict__ PtR,
    const float* __restrict__ PiG, const float* __restrict__ PiR,
    float* __restrict__ Gt, float* __restrict__ Gi, float* __restrict__ Racc)
{
    const int BKD = B_ * K_ * D_;
    int idx = blockIdx.x * 256 + threadIdx.x;
    if (idx >= BKD) return;
    float gt = 0.f, gi = 0.f, r = 0.f;
    #pragma unroll
    for (int c = 0; c < 8; ++c) { gt += PtG[(size_t)c * BKD + idx]; r += PtR[(size_t)c * BKD + idx]; }
    #pragma unroll
    for (int c = 0; c < 8; ++c) { gi += PiG[(size_t)c * BKD + idx]; r += PiR[(size_t)c * BKD + idx]; }
    Gt[idx] = gt; Gi[idx] = gi; Racc[idx] = r;
}

// ---------------------------------------------------------------------------
__global__ __launch_bounds__(256) void final_ln_kernel(
    const float* __restrict__ stateTmp, const float* __restrict__ Racc,
    const float* __restrict__ rs_t, const float* __restrict__ rs_i,
    const float* __restrict__ b_tspf, const float* __restrict__ b_ispf,
    const float* __restrict__ state_init, const float* __restrict__ value_init,
    const float* __restrict__ stn_g, const float* __restrict__ stn_b,
    const float* __restrict__ vn_g, const float* __restrict__ vn_b,
    float* __restrict__ outState, float* __restrict__ outValue)
{
    __shared__ float pre[D_];
    __shared__ float red[256];
    int idx = blockIdx.x;
    int row = idx & 127;
    int isVal = idx >> 7;
    int tid = threadIdx.x;
    if (!isVal) {
        float rt = rs_t[row], ri = rs_i[row];
        for (int d = tid; d < D_; d += 256)
            pre[d] = stateTmp[(size_t)row * D_ + d] + rt * b_tspf[d] + ri * b_ispf[d]
                   + state_init[(size_t)row * D_ + d];
    } else {
        for (int d = tid; d < D_; d += 256)
            pre[d] = Racc[(size_t)row * D_ + d] + value_init[(size_t)row * D_ + d];
    }
    __syncthreads();
    float s = 0.f;
    for (int d = tid; d < D_; d += 256) s += pre[d];
    red[tid] = s; __syncthreads();
    for (int off = 128; off > 0; off >>= 1) { if (tid < off) red[tid] += red[tid + off]; __syncthreads(); }
    float mu = red[0] / (float)D_;
    __syncthreads();
    float v = 0.f;
    for (int d = tid; d < D_; d += 256) { float t = pre[d] - mu; v += t * t; }
    red[tid] = v; __syncthreads();
    for (int off = 128; off > 0; off >>= 1) { if (tid < off) red[tid] += red[tid + off]; __syncthreads(); }
    float rstd = rsqrtf(red[0] / (float)D_ + EPS_LN);
    const float* g  = isVal ? vn_g : stn_g;
    const float* bb = isVal ? vn_b : stn_b;
    float* o = (isVal ? outValue : outState) + (size_t)row * D_;
    for (int d = tid; d < D_; d += 256) o[d] = (pre[d] - mu) * rstd * g[d] + bb[d];
}

// ---------------------------------------------------------------------------
extern "C" void kernel_launch(void* const* d_in, const int* in_sizes, int n_in,
                              void* d_out, int out_size, void* d_ws, size_t ws_size,
                              hipStream_t stream) {
    const float* text_values  = (const float*)d_in[0];
    const float* image_values = (const float*)d_in[1];
    const float* lstate_init  = (const float*)d_in[2];
    const float* lvalue_init  = (const float*)d_in[3];
    const float* text_mask    = (const float*)d_in[4];
    const float* image_mask   = (const float*)d_in[5];
    const float* t_sn_g = (const float*)d_in[6];
    const float* t_sn_b = (const float*)d_in[7];
    const float* t_tn_g = (const float*)d_in[8];
    const float* t_tn_b = (const float*)d_in[9];
    const float* t_su_w = (const float*)d_in[10];
    const float* t_su_b = (const float*)d_in[11];
    const float* t_tp_w = (const float*)d_in[12];
    const float* t_tp_b = (const float*)d_in[13];
    const float* t_m1_w = (const float*)d_in[14];
    const float* t_m1_b = (const float*)d_in[15];
    const float* t_m2_w = (const float*)d_in[16];
    const float* t_m2_b = (const float*)d_in[17];
    const float* i_sn_g = (const float*)d_in[18];
    const float* i_sn_b = (const float*)d_in[19];
    const float* i_tn_g = (const float*)d_in[20];
    const float* i_tn_b = (const float*)d_in[21];
    const float* i_su_w = (const float*)d_in[22];
    const float* i_su_b = (const float*)d_in[23];
    const float* i_tp_w = (const float*)d_in[24];
    const float* i_tp_b = (const float*)d_in[25];
    const float* i_m1_w = (const float*)d_in[26];
    const float* i_m1_b = (const float*)d_in[27];
    const float* i_m2_w = (const float*)d_in[28];
    const float* i_m2_b = (const float*)d_in[29];
    const float* tsn_g = (const float*)d_in[30];
    const float* tsn_b = (const float*)d_in[31];
    const float* isn_g = (const float*)d_in[32];
    const float* isn_b = (const float*)d_in[33];
    const float* stn_g = (const float*)d_in[34];
    const float* stn_b = (const float*)d_in[35];
    const float* vn_g  = (const float*)d_in[36];
    const float* vn_b  = (const float*)d_in[37];
    const float* tsp_w = (const float*)d_in[38];
    const float* tsp_b = (const float*)d_in[39];
    const float* isp_w = (const float*)d_in[40];
    const float* isp_b = (const float*)d_in[41];

    float* ws = (float*)d_ws;
    size_t o = 0;
    float* stats_mu = ws + o; o += 6272;
    float* stats_rs = ws + o; o += 6272;
    // --- zeroed block (contiguous) ---
    float* zeroBase = ws + o;
    float* b_su_t = ws + o; o += E_;
    float* b_su_i = ws + o; o += E_;
    float* b_tp_t = ws + o; o += E_;
    float* b_tp_i = ws + o; o += E_;
    float* b_tspf = ws + o; o += D_;
    float* b_ispf = ws + o; o += D_;
    float* t_t  = ws + o; o += (size_t)B_ * K_ * E_;
    float* t_i  = ws + o; o += (size_t)B_ * K_ * E_;
    float* c2_t = ws + o; o += (size_t)B_ * K_ * E_;
    float* c2_i = ws + o; o += (size_t)B_ * K_ * E_;
    float* state_tmp = ws + o; o += (size_t)B_ * K_ * D_;
    float* rs_t = ws + o; o += 128;
    float* rs_i = ws + o; o += 128;
    size_t zeroFloats = (size_t)(4 * E_ + 2 * D_ + 4 * B_ * K_ * E_ + B_ * K_ * D_ + 256);
    // --- end zeroed block ---
    ushort_t* AF_t = (ushort_t*)(ws + o); o += (size_t)B_ * ST_ * D_ / 2;
    ushort_t* AF_i = (ushort_t*)(ws + o); o += (size_t)B_ * SI_ * D_ / 2;
    ushort_t* WsuF_t = (ushort_t*)(ws + o); o += (size_t)D_ * E_ / 2;
    ushort_t* WsuF_i = (ushort_t*)(ws + o); o += (size_t)D_ * E_ / 2;
    ushort_t* sF_t = (ushort_t*)(ws + o); o += (size_t)B_ * ST_ * E_ / 2;
    ushort_t* sF_i = (ushort_t*)(ws + o); o += (size_t)B_ * SI_ * E_ / 2;
    ushort_t* MF_t = (ushort_t*)(ws + o); o += (size_t)B_ * K_ * E_ * E_ / 2;
    ushort_t* MF_i = (ushort_t*)(ws + o); o += (size_t)B_ * K_ * E_ * E_ / 2;
    ushort_t* XhF_t = (ushort_t*)(ws + o); o += (size_t)B_ * ST_ * D_ / 2;
    ushort_t* XhF_i = (ushort_t*)(ws + o); o += (size_t)B_ * SI_ * D_ / 2;
    ushort_t* XrF_t = (ushort_t*)(ws + o); o += (size_t)B_ * ST_ * D_ / 2;
    ushort_t* XrF_i = (ushort_t*)(ws + o); o += (size_t)B_ * SI_ * D_ / 2;
    ushort_t* EF_t  = (ushort_t*)(ws + o); o += (size_t)B_ * ST_ * K_ / 2;
    ushort_t* EF_i  = (ushort_t*)(ws + o); o += (size_t)B_ * SI_ * K_ / 2;
    const int BKD = B_ * K_ * D_;
    float* PtG = ws + o; o += (size_t)8 * BKD;
    float* PtR = ws + o; o += (size_t)8 * BKD;
    float* PiG = ws + o; o += (size_t)8 * BKD;
    float* PiR = ws + o; o += (size_t)8 * BKD;
    float* Gt   = ws + o; o += BKD;
    float* Gi   = ws + o; o += BKD;
    float* Racc = ws + o; o += BKD;

    float* outState = (float*)d_out;
    float* outValue = (float*)d_out + (size_t)B_ * K_ * D_;
    float* t2l = (float*)d_out + 2 * (size_t)B_ * K_ * D_;
    float* i2l = t2l + (size_t)B_ * ST_ * K_;

    hipMemsetAsync(zeroBase, 0, zeroFloats * sizeof(float), stream);

    ln_stats_kernel<<<1568, 256, 0, stream>>>(text_values, image_values, lvalue_init, stats_mu, stats_rs);

    fold_all_kernel<<<dim3(12, 12, 6), 256, 0, stream>>>(
        t_sn_b, t_su_w, t_su_b, b_su_t,
        i_sn_b, i_su_w, i_su_b, b_su_i,
        t_tn_b, t_tp_w, t_tp_b, b_tp_t,
        i_tn_b, i_tp_w, i_tp_b, b_tp_i,
        tsn_b, tsp_w, tsp_b, b_tspf,
        isn_b, isp_w, isp_b, b_ispf);

    tpack_kernel<<<dim3(96, 12), 256, 0, stream>>>(
        text_values, image_values, stats_mu, stats_rs,
        XrF_t, XhF_t, AF_t, XrF_i, XhF_i, AF_i);

    packB_kernel<<<96, 256, 0, stream>>>(t_su_w, t_sn_g, WsuF_t, D_, E_);
    packB_kernel<<<96, 256, 0, stream>>>(i_su_w, i_sn_g, WsuF_i, D_, E_);

    // t projections: t = LN(lat)@(g*W)+bias, split-K atomics
    sgemm_split_kernel<<<dim3(4, 2, 12), dim3(16, 16), 0, stream>>>(
        lvalue_init, t_tp_w, t_tn_g, b_tp_t, stats_mu, stats_rs, 6144, t_t,
        lvalue_init, i_tp_w, i_tn_g, b_tp_i, stats_mu, stats_rs, 6144, t_i,
        6, D_, E_);
    // c2 = t@W2 + m1_b
    sgemm_split_kernel<<<dim3(4, 2, 4), dim3(16, 16), 0, stream>>>(
        t_t, t_m1_w + (size_t)E_ * E_, nullptr, t_m1_b, nullptr, nullptr, 0, c2_t,
        t_i, i_m1_w + (size_t)E_ * E_, nullptr, i_m1_b, nullptr, nullptr, 0, c2_i,
        2, E_, E_);

    sproj_mfma_kernel<<<192, 256, 0, stream>>>(
        AF_t, WsuF_t, b_su_t, sF_t, AF_i, WsuF_i, b_su_i, sF_i);

    pack_M_kernel<<<8192, 256, 0, stream>>>(
        t_t, t_m1_w + 2 * (size_t)E_ * E_, t_m1_w, MF_t,
        t_i, i_m1_w + 2 * (size_t)E_ * E_, i_m1_w, MF_i);

    cross_mfma_kernel<<<dim3(48, K_, B_), 256, 0, stream>>>(
        sF_t, MF_t, c2_t, t_m2_w, t_m2_b, text_mask, t2l, EF_t, rs_t,
        sF_i, MF_i, c2_i, i_m2_w, i_m2_b, image_mask, i2l, EF_i, rs_i);

    einsum_mfma_kernel<<<dim3(3, 8, 4), 256, 0, stream>>>(
        EF_t, XhF_t, XrF_t, PtG, PtR,
        EF_i, XhF_i, XrF_i, PiG, PiR);

    reduce_parts_kernel<<<(BKD + 255) / 256, 256, 0, stream>>>(PtG, PtR, PiG, PiR, Gt, Gi, Racc);

    // state_tmp = Gt@(g*tsp_w) + Gi@(g*isp_w)
    sgemm_split_kernel<<<dim3(12, 2, 12), dim3(16, 16), 0, stream>>>(
        Gt, tsp_w, tsn_g, nullptr, nullptr, nullptr, 0, state_tmp,
        Gi, isp_w, isn_g, nullptr, nullptr, nullptr, 0, state_tmp,
        6, D_, D_);

    final_ln_kernel<<<2 * B_ * K_, 256, 0, stream>>>(
        state_tmp, Racc, rs_t, rs_i, b_tspf, b_ispf,
        lstate_init, lvalue_init, stn_g, stn_b, vn_g, vn_b, outState, outValue);
}